// Round 2
// baseline (262.525 us; speedup 1.0000x reference)
//
#include <hip/hip_runtime.h>
#include <hip/hip_bf16.h>

#define T_ 4
#define B_ 4
#define C_ 256
#define H_ 32
#define W_ 32
#define TB_ 16
#define Hh_ 16
#define Wh_ 16
#define INVS2 0.70710678118654752440f
#define EPSBN 1e-5f

// Canonical weight arena offsets (bf16 elements)
#define OFF_HW   0
#define OFF_W1   4096
#define OFF_B1   4352
#define OFF_W2   4368
#define OFF_B2   6672
#define OFF_G1   6688
#define OFF_BE1  7200
#define OFF_G2   7712
#define OFF_BE2  8736
#define OFF_G3   9760
#define OFF_BE3  10016
#define OFF_G4   10272
#define OFF_BE4  10528
#define OFF_G5   10784
#define OFF_BE5  11040
#define W_TOTAL  11296

struct WPtrs { const void* p[15]; };

// ---------------------------------------------------------------------------
// Dtype sniff: decide if inputs are fp32 (flag=1) or bf16 (flag=0).
// bf16 N(0,1) data: no element has |v| >= 128 (exp >= 134).
// fp32 data read as uint16: low halves have uniform exponent bits -> ~23% huge.
// ---------------------------------------------------------------------------
__global__ __launch_bounds__(256) void k_sniff(const unsigned short* __restrict__ xr,
                                               int* __restrict__ flag) {
    int tid = threadIdx.x;
    int cnt = 0;
    for (int i = tid; i < 2048; i += 256) {
        int e = (xr[i] >> 7) & 0xFF;
        if (e >= 134) cnt++;
    }
    __shared__ int sh[256];
    sh[tid] = cnt;
    __syncthreads();
    for (int o = 128; o > 0; o >>= 1) {
        if (tid < o) sh[tid] += sh[tid + o];
        __syncthreads();
    }
    if (tid == 0) *flag = (sh[0] >= 32) ? 1 : 0;
}

// ---------------------------------------------------------------------------
// Canonicalize all weight arrays to bf16 arena.
// ---------------------------------------------------------------------------
__global__ __launch_bounds__(256) void k_convert(WPtrs wp,
                                                 __hip_bfloat16* __restrict__ wc,
                                                 const int* __restrict__ flag) {
    const int sizes[15] = {4096, 256, 16, 2304, 16, 512, 512, 1024, 1024,
                           256, 256, 256, 256, 256, 256};
    int f = *flag;
    int i = blockIdx.x * 256 + threadIdx.x;
    if (i >= W_TOTAL) return;
    int seg = 0, off = 0;
    while (i >= off + sizes[seg]) { off += sizes[seg]; seg++; }
    int j = i - off;
    float v = f ? ((const float*)wp.p[seg])[j]
                : __bfloat162float(((const __hip_bfloat16*)wp.p[seg])[j]);
    wc[i] = __float2bfloat16(v);
}

// ---------------------------------------------------------------------------
// LIF over T -> uint8 spikes (exact).
// ---------------------------------------------------------------------------
__global__ __launch_bounds__(256) void k_lif(const void* __restrict__ x_,
                                             const int* __restrict__ flag,
                                             unsigned char* __restrict__ s) {
    const int N = B_ * C_ * H_ * W_;          // 1,048,576
    int n = blockIdx.x * 256 + threadIdx.x;
    int f = *flag;
    const float* xf = (const float*)x_;
    const __hip_bfloat16* xb = (const __hip_bfloat16*)x_;
    float v = 0.f;
    #pragma unroll
    for (int t = 0; t < T_; ++t) {
        size_t idx = (size_t)t * N + n;
        float xv = f ? xf[idx] : __bfloat162float(xb[idx]);
        v += (xv - v) * 0.5f;                 // tau = 2
        unsigned char sp = (v - 1.0f >= 0.f) ? 1 : 0;
        s[idx] = sp;
        if (sp) v = 0.f;
    }
}

// ---------------------------------------------------------------------------
// Haar along W -> int8 codes (value = code * INVS2, exact; +-0.5 gate is
// identity on {0, +-0.707, +-1.414} so it is folded away).
// ---------------------------------------------------------------------------
__global__ __launch_bounds__(256) void k_haarw(const unsigned char* __restrict__ s,
                                               signed char* __restrict__ l1) {
    int n = blockIdx.x * 256 + threadIdx.x;   // TB*C*H*Wh = 2,097,152
    int wv = n & 15;
    int h  = (n >> 4) & 31;
    int c  = (n >> 9) & 255;
    int tb = n >> 17;
    size_t sbase = (((size_t)tb * C_ + c) * H_ + h) * W_ + 2 * wv;
    int s0 = s[sbase], s1 = s[sbase + 1];
    size_t lbase = (((size_t)tb * 512 + c) * H_ + h) * Wh_ + wv;
    l1[lbase] = (signed char)(s0 + s1);                       // low code
    l1[lbase + (size_t)C_ * H_ * Wh_] = (signed char)(s0 - s1); // high code
}

// ---------------------------------------------------------------------------
// BN1 stats from int8 codes, layout (TB, 512, 512).
// ---------------------------------------------------------------------------
__global__ __launch_bounds__(256) void k_stats_l1(const signed char* __restrict__ codes,
                                                  const __hip_bfloat16* __restrict__ g,
                                                  const __hip_bfloat16* __restrict__ bta,
                                                  float* __restrict__ scale,
                                                  float* __restrict__ shift) {
    int c = blockIdx.x;                        // 512
    int tid = threadIdx.x;
    float sum = 0.f, ss = 0.f;
    for (int tb = 0; tb < TB_; ++tb) {
        const signed char* p = codes + ((size_t)tb * 512 + c) * 512;
        for (int i = tid; i < 512; i += 256) {
            float v = (float)p[i];
            sum += v; ss += v * v;
        }
    }
    __shared__ float rs[256], rq[256];
    rs[tid] = sum; rq[tid] = ss;
    __syncthreads();
    for (int o = 128; o > 0; o >>= 1) {
        if (tid < o) { rs[tid] += rs[tid + o]; rq[tid] += rq[tid + o]; }
        __syncthreads();
    }
    if (tid == 0) {
        float n = (float)(TB_ * 512);
        float mean = (rs[0] * INVS2) / n;
        float msq  = (rq[0] * 0.5f) / n;
        float var  = fmaxf(msq - mean * mean, 0.f);
        float rstd = rsqrtf(var + EPSBN);
        float sc = __bfloat162float(g[c]) * rstd;
        scale[c] = sc;
        shift[c] = __bfloat162float(bta[c]) - mean * sc;
    }
}

// ---------------------------------------------------------------------------
// Generic per-channel stats from a bf16 buffer (TB, nch, sp).
// ---------------------------------------------------------------------------
__global__ __launch_bounds__(256) void k_stats_bf16(const __hip_bfloat16* __restrict__ buf,
                                                    const __hip_bfloat16* __restrict__ g,
                                                    const __hip_bfloat16* __restrict__ bta,
                                                    float* __restrict__ scale,
                                                    float* __restrict__ shift,
                                                    int nch, int sp) {
    int c = blockIdx.x;
    int tid = threadIdx.x;
    float sum = 0.f, ss = 0.f;
    for (int tb = 0; tb < TB_; ++tb) {
        const __hip_bfloat16* p = buf + ((size_t)tb * nch + c) * sp;
        for (int i = tid; i < sp; i += 256) {
            float v = __bfloat162float(p[i]);
            sum += v; ss += v * v;
        }
    }
    __shared__ float rs[256], rq[256];
    rs[tid] = sum; rq[tid] = ss;
    __syncthreads();
    for (int o = 128; o > 0; o >>= 1) {
        if (tid < o) { rs[tid] += rs[tid + o]; rq[tid] += rq[tid + o]; }
        __syncthreads();
    }
    if (tid == 0) {
        float n = (float)(TB_ * sp);
        float mean = rs[0] / n;
        float var = fmaxf(rq[0] / n - mean * mean, 0.f);
        float rstd = rsqrtf(var + EPSBN);
        float sc = __bfloat162float(g[c]) * rstd;
        scale[c] = sc;
        shift[c] = __bfloat162float(bta[c]) - mean * sc;
    }
}

// ---------------------------------------------------------------------------
// BN1-apply + Haar along H + elementwise gate + per-band energy gate
// -> l2 bf16 (TB, 1024, 16, 16). One block per (tb, c).
// ---------------------------------------------------------------------------
__global__ __launch_bounds__(256) void k_stage2(const signed char* __restrict__ l1,
                                                const float* __restrict__ sc,
                                                const float* __restrict__ sh,
                                                __hip_bfloat16* __restrict__ l2) {
    int blk = blockIdx.x;                 // TB*C = 4096
    int c = blk & 255;
    int tb = blk >> 8;
    int tid = threadIdx.x;

    __shared__ float lo[H_ * Wh_];
    __shared__ float hi[H_ * Wh_];
    const signed char* plo = l1 + (((size_t)tb * 512) + c) * (H_ * Wh_);
    const signed char* phi = l1 + (((size_t)tb * 512) + 256 + c) * (H_ * Wh_);
    float slo = sc[c] * INVS2, tlo = sh[c];
    float shi = sc[256 + c] * INVS2, thi = sh[256 + c];
    for (int i = tid; i < H_ * Wh_; i += 256) {
        lo[i] = (float)plo[i] * slo + tlo;
        hi[i] = (float)phi[i] * shi + thi;
    }
    __syncthreads();

    int w = tid & 15, v = tid >> 4;
    float a = lo[(2 * v) * Wh_ + w], b = lo[(2 * v + 1) * Wh_ + w];
    float zLL = (a + b) * INVS2;
    float zHL = (a - b) * INVS2;
    a = hi[(2 * v) * Wh_ + w]; b = hi[(2 * v + 1) * Wh_ + w];
    float zLH = (a + b) * INVS2;
    float zHH = (a - b) * INVS2;
    zLL = (fabsf(zLL) - 0.5f >= 0.f) ? zLL : 0.f;
    zHL = (fabsf(zHL) - 0.5f >= 0.f) ? zHL : 0.f;
    zLH = (fabsf(zLH) - 0.5f >= 0.f) ? zLH : 0.f;
    zHH = (fabsf(zHH) - 0.5f >= 0.f) ? zHH : 0.f;

    __shared__ float4 red[256];
    red[tid] = make_float4(zLL * zLL, zHL * zHL, zLH * zLH, zHH * zHH);
    __syncthreads();
    for (int o = 128; o > 0; o >>= 1) {
        if (tid < o) {
            red[tid].x += red[tid + o].x;
            red[tid].y += red[tid + o].y;
            red[tid].z += red[tid + o].z;
            red[tid].w += red[tid + o].w;
        }
        __syncthreads();
    }
    float4 E = red[0];
    float fLL = (E.x * (1.f / 256.f) > 0.01f) ? 1.f : 0.f;
    float fHL = (E.y * (1.f / 256.f) > 0.02f) ? 1.f : 0.f;
    float fLH = (E.z * (1.f / 256.f) > 0.02f) ? 1.f : 0.f;
    float fHH = (E.w * (1.f / 256.f) > 0.05f) ? 1.f : 0.f;

    size_t ob = (((size_t)tb * 1024) + c) * 256 + tid;
    l2[ob]               = __float2bfloat16(zLL * fLL);
    l2[ob + 256u * 256u] = __float2bfloat16(zHL * fHL);
    l2[ob + 512u * 256u] = __float2bfloat16(zLH * fLH);
    l2[ob + 768u * 256u] = __float2bfloat16(zHH * fHH);
}

// ---------------------------------------------------------------------------
// BN2-apply + block-diagonal channel matmul -> h bf16.
// Out channel g*16+k = sum_d l2n[g*16+d] * hw[g/4][d][k].
// ---------------------------------------------------------------------------
__global__ __launch_bounds__(256) void k_mix(const __hip_bfloat16* __restrict__ l2,
                                             const float* __restrict__ sc,
                                             const float* __restrict__ sh,
                                             const __hip_bfloat16* __restrict__ hw,
                                             __hip_bfloat16* __restrict__ hbuf) {
    int blk = blockIdx.x;                 // TB*64 = 1024
    int g = blk & 63;
    int tb = blk >> 6;
    int tid = threadIdx.x;

    __shared__ float in_n[16][256];
    __shared__ float wt[16][16];
    wt[tid >> 4][tid & 15] = __bfloat162float(hw[(g >> 2) * 256 + tid]);
    const __hip_bfloat16* base = l2 + (((size_t)tb * 1024) + g * 16) * 256;
    #pragma unroll
    for (int d = 0; d < 16; ++d) {
        int ch = g * 16 + d;
        in_n[d][tid] = __bfloat162float(base[d * 256 + tid]) * sc[ch] + sh[ch];
    }
    __syncthreads();

    float acc[16];
    #pragma unroll
    for (int k = 0; k < 16; ++k) acc[k] = 0.f;
    #pragma unroll
    for (int d = 0; d < 16; ++d) {
        float xv = in_n[d][tid];
        #pragma unroll
        for (int k = 0; k < 16; ++k) acc[k] += xv * wt[d][k];
    }
    __hip_bfloat16* out = hbuf + (((size_t)tb * 1024) + g * 16) * 256;
    #pragma unroll
    for (int k = 0; k < 16; ++k) out[k * 256 + tid] = __float2bfloat16(acc[k]);
}

// ---------------------------------------------------------------------------
// Inverse Haar (H then W) -> rec bf16 (TB, C, H, W).
// ---------------------------------------------------------------------------
__global__ __launch_bounds__(256) void k_inv(const __hip_bfloat16* __restrict__ hbuf,
                                             __hip_bfloat16* __restrict__ rec) {
    int blk = blockIdx.x;                 // TB*C = 4096
    int c = blk & 255;
    int tb = blk >> 8;
    int tid = threadIdx.x;
    int uw = tid & 15, uh = tid >> 4;
    size_t base = ((size_t)tb * 1024) * 256;
    float LL = __bfloat162float(hbuf[base + ((size_t)(c)) * 256 + tid]);
    float HL = __bfloat162float(hbuf[base + ((size_t)(256 + c)) * 256 + tid]);
    float LH = __bfloat162float(hbuf[base + ((size_t)(512 + c)) * 256 + tid]);
    float HH = __bfloat162float(hbuf[base + ((size_t)(768 + c)) * 256 + tid]);
    float v00 = 0.5f * (LL + HL + LH + HH);
    float v01 = 0.5f * (LL + HL - LH - HH);
    float v10 = 0.5f * (LL - HL + LH - HH);
    float v11 = 0.5f * (LL - HL - LH + HH);
    __hip_bfloat16* out = rec + (((size_t)tb * 256) + c) * 1024;
    out[(2 * uh) * 32 + 2 * uw]         = __float2bfloat16(v00);
    out[(2 * uh) * 32 + 2 * uw + 1]     = __float2bfloat16(v01);
    out[(2 * uh + 1) * 32 + 2 * uw]     = __float2bfloat16(v10);
    out[(2 * uh + 1) * 32 + 2 * uw + 1] = __float2bfloat16(v11);
}

// ---------------------------------------------------------------------------
// Grouped 1x1 + 3x3 convs on spikes -> c1, c2 bf16.
// ---------------------------------------------------------------------------
__global__ __launch_bounds__(256) void k_conv(const unsigned char* __restrict__ s,
                                              const __hip_bfloat16* __restrict__ w1,
                                              const __hip_bfloat16* __restrict__ b1,
                                              const __hip_bfloat16* __restrict__ w2,
                                              const __hip_bfloat16* __restrict__ b2,
                                              __hip_bfloat16* __restrict__ c1,
                                              __hip_bfloat16* __restrict__ c2) {
    __shared__ float W1[16][16];
    __shared__ float W2[16][16][9];
    __shared__ float B1[16], B2[16];
    int tid = threadIdx.x;
    W1[tid >> 4][tid & 15] = __bfloat162float(w1[tid]);
    for (int i = tid; i < 2304; i += 256)
        W2[i / 144][(i / 9) & 15][i % 9] = __bfloat162float(w2[i]);
    if (tid < 16) {
        B1[tid] = __bfloat162float(b1[tid]);
        B2[tid] = __bfloat162float(b2[tid]);
    }
    __syncthreads();

    int n = blockIdx.x * 256 + tid;       // TB*NB*1024 = 262,144
    int pix = n & 1023;
    int nb = (n >> 10) & 15;
    int tb = n >> 14;
    int h = pix >> 5, w = pix & 31;
    const unsigned char* sb = s + (((size_t)tb * 256) + nb * 16) * 1024;

    float a1[16], a2[16];
    #pragma unroll
    for (int k = 0; k < 16; ++k) { a1[k] = B1[k]; a2[k] = B2[k]; }

    for (int d = 0; d < 16; ++d) {
        float sv[9];
        #pragma unroll
        for (int dy = 0; dy < 3; ++dy) {
            #pragma unroll
            for (int dx = 0; dx < 3; ++dx) {
                int hh = h + dy - 1, ww = w + dx - 1;
                sv[dy * 3 + dx] = (hh >= 0 && hh < 32 && ww >= 0 && ww < 32)
                    ? (float)sb[d * 1024 + hh * 32 + ww] : 0.f;
            }
        }
        float ctr = sv[4];
        #pragma unroll
        for (int k = 0; k < 16; ++k) {
            a1[k] += W1[k][d] * ctr;
            float t = 0.f;
            #pragma unroll
            for (int tap = 0; tap < 9; ++tap) t += W2[k][d][tap] * sv[tap];
            a2[k] += t;
        }
    }
    __hip_bfloat16* o1 = c1 + (((size_t)tb * 256) + nb * 16) * 1024;
    __hip_bfloat16* o2 = c2 + (((size_t)tb * 256) + nb * 16) * 1024;
    #pragma unroll
    for (int k = 0; k < 16; ++k) {
        o1[k * 1024 + pix] = __float2bfloat16(a1[k]);
        o2[k * 1024 + pix] = __float2bfloat16(a2[k]);
    }
}

// ---------------------------------------------------------------------------
// Final combine: out = bn3(rec) + bn4(c1) + bn5(c2); dtype per flag.
// ---------------------------------------------------------------------------
__global__ __launch_bounds__(256) void k_final(const __hip_bfloat16* __restrict__ rec,
                                               const __hip_bfloat16* __restrict__ c1,
                                               const __hip_bfloat16* __restrict__ c2,
                                               const float* __restrict__ stats,
                                               const int* __restrict__ flag,
                                               void* __restrict__ out_) {
    int n = blockIdx.x * 256 + threadIdx.x;   // 4,194,304
    int c = (n >> 10) & 255;
    const float* sc3 = stats + 3072; const float* sh3 = stats + 3328;
    const float* sc4 = stats + 3584; const float* sh4 = stats + 3840;
    const float* sc5 = stats + 4096; const float* sh5 = stats + 4352;
    float v = __bfloat162float(rec[n]) * sc3[c] + sh3[c]
            + __bfloat162float(c1[n]) * sc4[c] + sh4[c]
            + __bfloat162float(c2[n]) * sc5[c] + sh5[c];
    if (*flag) ((float*)out_)[n] = v;
    else       ((__hip_bfloat16*)out_)[n] = __float2bfloat16(v);
}

// ---------------------------------------------------------------------------
extern "C" void kernel_launch(void* const* d_in, const int* in_sizes, int n_in,
                              void* d_out, int out_size, void* d_ws, size_t ws_size,
                              hipStream_t stream) {
    char* ws = (char*)d_ws;
    unsigned char* s_u8   = (unsigned char*)ws;                                // 4 MB
    signed char* l1c      = (signed char*)(ws + ((size_t)4 << 20));            // 4 MB
    __hip_bfloat16* bufA  = (__hip_bfloat16*)(ws + ((size_t)8 << 20));         // 8 MB: l2, later c1
    __hip_bfloat16* bufB  = (__hip_bfloat16*)(ws + ((size_t)16 << 20));        // 8 MB: h, later c2
    __hip_bfloat16* bufC  = (__hip_bfloat16*)(ws + ((size_t)24 << 20));        // 8 MB: rec
    __hip_bfloat16* wc    = (__hip_bfloat16*)(ws + ((size_t)32 << 20));        // ~22.6 KB
    float* stats          = (float*)(ws + ((size_t)32 << 20) + (64 << 10));    // 18.4 KB
    int* flag             = (int*)(ws + ((size_t)32 << 20) + (128 << 10));

    float* sc1 = stats;        float* sh1 = stats + 512;
    float* sc2 = stats + 1024; float* sh2 = stats + 2048;
    float* sc3 = stats + 3072; float* sh3 = stats + 3328;
    float* sc4 = stats + 3584; float* sh4 = stats + 3840;
    float* sc5 = stats + 4096; float* sh5 = stats + 4352;

    WPtrs wp;
    for (int i = 0; i < 15; ++i) wp.p[i] = d_in[i + 1];

    dim3 blk(256);

    k_sniff<<<dim3(1), blk, 0, stream>>>((const unsigned short*)d_in[0], flag);
    k_convert<<<dim3(45), blk, 0, stream>>>(wp, wc, flag);
    k_lif<<<dim3(4096), blk, 0, stream>>>(d_in[0], flag, s_u8);
    k_haarw<<<dim3(8192), blk, 0, stream>>>(s_u8, l1c);
    k_stats_l1<<<dim3(512), blk, 0, stream>>>(l1c, wc + OFF_G1, wc + OFF_BE1, sc1, sh1);
    k_stage2<<<dim3(4096), blk, 0, stream>>>(l1c, sc1, sh1, bufA);
    k_stats_bf16<<<dim3(1024), blk, 0, stream>>>(bufA, wc + OFF_G2, wc + OFF_BE2, sc2, sh2, 1024, 256);
    k_mix<<<dim3(1024), blk, 0, stream>>>(bufA, sc2, sh2, wc + OFF_HW, bufB);
    k_inv<<<dim3(4096), blk, 0, stream>>>(bufB, bufC);
    k_stats_bf16<<<dim3(256), blk, 0, stream>>>(bufC, wc + OFF_G3, wc + OFF_BE3, sc3, sh3, 256, 1024);
    k_conv<<<dim3(1024), blk, 0, stream>>>(s_u8, wc + OFF_W1, wc + OFF_B1, wc + OFF_W2, wc + OFF_B2, bufA, bufB);
    k_stats_bf16<<<dim3(256), blk, 0, stream>>>(bufA, wc + OFF_G4, wc + OFF_BE4, sc4, sh4, 256, 1024);
    k_stats_bf16<<<dim3(256), blk, 0, stream>>>(bufB, wc + OFF_G5, wc + OFF_BE5, sc5, sh5, 256, 1024);
    k_final<<<dim3(16384), blk, 0, stream>>>(bufC, bufA, bufB, stats, flag, d_out);
}

// Round 3
// 207.829 us; speedup vs baseline: 1.2632x; 1.2632x over previous
//
#include <hip/hip_runtime.h>
#include <hip/hip_bf16.h>

#define T_ 4
#define B_ 4
#define C_ 256
#define H_ 32
#define W_ 32
#define TB_ 16
#define Hh_ 16
#define Wh_ 16
#define INVS2 0.70710678118654752440f
#define EPSBN 1e-5f

// Canonical weight arena offsets (bf16 elements)
#define OFF_HW   0
#define OFF_W1   4096
#define OFF_B1   4352
#define OFF_W2   4368
#define OFF_B2   6672
#define OFF_G1   6688
#define OFF_BE1  7200
#define OFF_G2   7712
#define OFF_BE2  8736
#define OFF_G3   9760
#define OFF_BE3  10016
#define OFF_G4   10272
#define OFF_BE4  10528
#define OFF_G5   10784
#define OFF_BE5  11040
#define W_TOTAL  11296
#define NSUMS    3072          // raw sums: BN1 (1024) + BN2 (2048)

struct WPtrs { const void* p[15]; };

__device__ inline float bf2f(__hip_bfloat16 v) { return __bfloat162float(v); }

// ---------------------------------------------------------------------------
// Dtype sniff: inputs fp32 (flag=1) or bf16 (flag=0).
// ---------------------------------------------------------------------------
__global__ __launch_bounds__(256) void k_sniff(const unsigned short* __restrict__ xr,
                                               int* __restrict__ flag) {
    int tid = threadIdx.x;
    int cnt = 0;
    for (int i = tid; i < 2048; i += 256) {
        int e = (xr[i] >> 7) & 0xFF;
        if (e >= 134) cnt++;
    }
    __shared__ int sh[256];
    sh[tid] = cnt;
    __syncthreads();
    for (int o = 128; o > 0; o >>= 1) {
        if (tid < o) sh[tid] += sh[tid + o];
        __syncthreads();
    }
    if (tid == 0) *flag = (sh[0] >= 32) ? 1 : 0;
}

// ---------------------------------------------------------------------------
// Canonicalize weights to bf16 arena + zero the raw-sums region.
// ---------------------------------------------------------------------------
__global__ __launch_bounds__(256) void k_convert(WPtrs wp,
                                                 __hip_bfloat16* __restrict__ wc,
                                                 float* __restrict__ sums,
                                                 const int* __restrict__ flag) {
    const int sizes[15] = {4096, 256, 16, 2304, 16, 512, 512, 1024, 1024,
                           256, 256, 256, 256, 256, 256};
    int f = *flag;
    int i = blockIdx.x * 256 + threadIdx.x;
    if (i < W_TOTAL) {
        int seg = 0, off = 0;
        while (i >= off + sizes[seg]) { off += sizes[seg]; seg++; }
        int j = i - off;
        float v = f ? ((const float*)wp.p[seg])[j]
                    : bf2f(((const __hip_bfloat16*)wp.p[seg])[j]);
        wc[i] = __float2bfloat16(v);
    }
    int z = i - W_TOTAL;
    if (z >= 0 && z < NSUMS) sums[z] = 0.f;
}

// ---------------------------------------------------------------------------
// Fused LIF + Haar-W. Thread = (b, c, h, w-pair), loops t.
// Writes u8 spikes + i8 Haar codes; accumulates BN1 raw sums (atomics).
// sums1 layout: sum[512] | ss[512]; lo-channel=c, hi-channel=256+c.
// ---------------------------------------------------------------------------
__global__ __launch_bounds__(256) void k_lifhaar(const void* __restrict__ x_,
                                                 const int* __restrict__ flag,
                                                 unsigned char* __restrict__ s,
                                                 signed char* __restrict__ l1,
                                                 float* __restrict__ sums1) {
    int bid = blockIdx.x;                      // 2048 = b(4) * c(256) * half(2)
    int tid = threadIdx.x;
    int half = bid & 1;
    int c = (bid >> 1) & 255;
    int b = bid >> 9;
    int wp = tid & 15;
    int hl = tid >> 4;
    int h = half * 16 + hl;
    int f = *flag;
    const float* xf = (const float*)x_;
    const unsigned int* xb = (const unsigned int*)x_;
    int n = ((b * 256 + c) * 32 + h) * 32 + 2 * wp;

    float v0 = 0.f, v1 = 0.f;
    float aL = 0.f, qL = 0.f, aH = 0.f, qH = 0.f;
    #pragma unroll
    for (int t = 0; t < T_; ++t) {
        size_t idx = (size_t)t * 1048576 + n;
        float x0, x1;
        if (f) {
            float2 xx = *(const float2*)(xf + idx);
            x0 = xx.x; x1 = xx.y;
        } else {
            unsigned int u = xb[idx >> 1];
            x0 = __uint_as_float(u << 16);
            x1 = __uint_as_float(u & 0xffff0000u);
        }
        v0 += (x0 - v0) * 0.5f;
        v1 += (x1 - v1) * 0.5f;
        float s0 = (v0 >= 1.f) ? 1.f : 0.f;
        float s1 = (v1 >= 1.f) ? 1.f : 0.f;
        v0 *= (1.f - s0);
        v1 *= (1.f - s1);
        int tb = t * 4 + b;
        ((uchar2*)s)[(size_t)(tb * 256 + c) * 512 + h * 16 + wp] =
            make_uchar2((unsigned char)s0, (unsigned char)s1);
        float cl = s0 + s1, ch = s0 - s1;
        size_t lb = (((size_t)tb * 512 + c) * 32 + h) * 16 + wp;
        l1[lb] = (signed char)(int)cl;
        l1[lb + (size_t)256 * 512] = (signed char)(int)ch;
        aL += cl; qL += cl * cl; aH += ch; qH += ch * ch;
    }
    __shared__ float4 red[256];
    red[tid] = make_float4(aL, qL, aH, qH);
    __syncthreads();
    for (int o = 128; o > 0; o >>= 1) {
        if (tid < o) {
            red[tid].x += red[tid + o].x; red[tid].y += red[tid + o].y;
            red[tid].z += red[tid + o].z; red[tid].w += red[tid + o].w;
        }
        __syncthreads();
    }
    if (tid == 0) {
        atomicAdd(&sums1[c],            red[0].x);
        atomicAdd(&sums1[512 + c],      red[0].y);
        atomicAdd(&sums1[256 + c],      red[0].z);
        atomicAdd(&sums1[768 + c],      red[0].w);
    }
}

// ---------------------------------------------------------------------------
// BN1-apply (from raw sums) + Haar-H + elementwise gate + energy gate
// -> l2 bf16 (TB, 1024, 16, 16); accumulates BN2 raw sums.
// sums2 layout: sum[1024] | ss[1024].
// ---------------------------------------------------------------------------
__global__ __launch_bounds__(256) void k_stage2(const signed char* __restrict__ l1,
                                                const float* __restrict__ sums1,
                                                const __hip_bfloat16* __restrict__ wc,
                                                float* __restrict__ sums2,
                                                __hip_bfloat16* __restrict__ l2) {
    int blk = blockIdx.x;                 // TB*C = 4096
    int c = blk & 255;
    int tb = blk >> 8;
    int tid = threadIdx.x;

    // BN1 coefficients from raw code sums (values = code * INVS2)
    const float nrm = 1.f / 8192.f;       // TB * H * Wh
    float mL = sums1[c] * INVS2 * nrm;
    float vL = fmaxf(sums1[512 + c] * 0.5f * nrm - mL * mL, 0.f);
    float sL = bf2f(wc[OFF_G1 + c]) * rsqrtf(vL + EPSBN);
    float tL = bf2f(wc[OFF_BE1 + c]) - mL * sL;
    float mH = sums1[256 + c] * INVS2 * nrm;
    float vH = fmaxf(sums1[768 + c] * 0.5f * nrm - mH * mH, 0.f);
    float sH = bf2f(wc[OFF_G1 + 256 + c]) * rsqrtf(vH + EPSBN);
    float tH = bf2f(wc[OFF_BE1 + 256 + c]) - mH * sH;

    __shared__ float lo[H_ * Wh_];
    __shared__ float hi[H_ * Wh_];
    const signed char* plo = l1 + (((size_t)tb * 512) + c) * (H_ * Wh_);
    const signed char* phi = l1 + (((size_t)tb * 512) + 256 + c) * (H_ * Wh_);
    float slo = sL * INVS2, shi = sH * INVS2;
    for (int i = tid; i < H_ * Wh_; i += 256) {
        lo[i] = (float)plo[i] * slo + tL;
        hi[i] = (float)phi[i] * shi + tH;
    }
    __syncthreads();

    int w = tid & 15, v = tid >> 4;
    float a = lo[(2 * v) * Wh_ + w], b = lo[(2 * v + 1) * Wh_ + w];
    float zLL = (a + b) * INVS2;
    float zHL = (a - b) * INVS2;
    a = hi[(2 * v) * Wh_ + w]; b = hi[(2 * v + 1) * Wh_ + w];
    float zLH = (a + b) * INVS2;
    float zHH = (a - b) * INVS2;
    zLL = (fabsf(zLL) - 0.5f >= 0.f) ? zLL : 0.f;
    zHL = (fabsf(zHL) - 0.5f >= 0.f) ? zHL : 0.f;
    zLH = (fabsf(zLH) - 0.5f >= 0.f) ? zLH : 0.f;
    zHH = (fabsf(zHH) - 0.5f >= 0.f) ? zHH : 0.f;

    __shared__ float4 red[256];           // squares (energy + BN ss)
    __shared__ float4 red2[256];          // sums (BN mean)
    red[tid]  = make_float4(zLL * zLL, zHL * zHL, zLH * zLH, zHH * zHH);
    red2[tid] = make_float4(zLL, zHL, zLH, zHH);
    __syncthreads();
    for (int o = 128; o > 0; o >>= 1) {
        if (tid < o) {
            red[tid].x += red[tid + o].x;   red[tid].y += red[tid + o].y;
            red[tid].z += red[tid + o].z;   red[tid].w += red[tid + o].w;
            red2[tid].x += red2[tid + o].x; red2[tid].y += red2[tid + o].y;
            red2[tid].z += red2[tid + o].z; red2[tid].w += red2[tid + o].w;
        }
        __syncthreads();
    }
    float4 E = red[0];
    float fLL = (E.x * (1.f / 256.f) > 0.01f) ? 1.f : 0.f;
    float fHL = (E.y * (1.f / 256.f) > 0.02f) ? 1.f : 0.f;
    float fLH = (E.z * (1.f / 256.f) > 0.02f) ? 1.f : 0.f;
    float fHH = (E.w * (1.f / 256.f) > 0.05f) ? 1.f : 0.f;

    if (tid == 0) {
        atomicAdd(&sums2[c],              fLL * red2[0].x);
        atomicAdd(&sums2[1024 + c],       fLL * red[0].x);
        atomicAdd(&sums2[256 + c],        fHL * red2[0].y);
        atomicAdd(&sums2[1024 + 256 + c], fHL * red[0].y);
        atomicAdd(&sums2[512 + c],        fLH * red2[0].z);
        atomicAdd(&sums2[1024 + 512 + c], fLH * red[0].z);
        atomicAdd(&sums2[768 + c],        fHH * red2[0].w);
        atomicAdd(&sums2[1024 + 768 + c], fHH * red[0].w);
    }

    size_t ob = (((size_t)tb * 1024) + c) * 256 + tid;
    l2[ob]               = __float2bfloat16(zLL * fLL);
    l2[ob + 256u * 256u] = __float2bfloat16(zHL * fHL);
    l2[ob + 512u * 256u] = __float2bfloat16(zLH * fLH);
    l2[ob + 768u * 256u] = __float2bfloat16(zHH * fHH);
}

// ---------------------------------------------------------------------------
// Fused BN2-apply + block channel matmul + inverse Haar -> rec bf16.
// Block = (tb, cg) with cg in [0,16); thread = quarter-res pixel (16x16).
// For q in 0..3: h_q[k] = sum_d l2n[q*256+cg*16+d] * hw[q*4+cg/4][d][k].
// rec channel cg*16+k gets the 2x2 inverse-Haar of (h_0..h_3)[k].
// ---------------------------------------------------------------------------
__global__ __launch_bounds__(256) void k_mixinv(const __hip_bfloat16* __restrict__ l2,
                                                const float* __restrict__ sums2,
                                                const __hip_bfloat16* __restrict__ wc,
                                                __hip_bfloat16* __restrict__ rec) {
    int bid = blockIdx.x;                 // 256 = tb(16) * cg(16)
    int cg = bid & 15;
    int tb = bid >> 4;
    int tid = threadIdx.x;

    __shared__ float wt[4][16][16];       // [q][d][k]
    __shared__ float bsc[64], bsh[64];    // BN2 scale/shift for (q,d)
    for (int i = tid; i < 1024; i += 256) {
        int q = i >> 8, rem = i & 255, d = rem >> 4, k = rem & 15;
        int nb = q * 4 + (cg >> 2);
        wt[q][d][k] = bf2f(wc[OFF_HW + nb * 256 + d * 16 + k]);
    }
    if (tid < 64) {
        int q = tid >> 4, d = tid & 15;
        int ch = q * 256 + cg * 16 + d;
        float m = sums2[ch] * (1.f / 4096.f);
        float var = fmaxf(sums2[1024 + ch] * (1.f / 4096.f) - m * m, 0.f);
        float sc = bf2f(wc[OFF_G2 + ch]) * rsqrtf(var + EPSBN);
        bsc[tid] = sc;
        bsh[tid] = bf2f(wc[OFF_BE2 + ch]) - m * sc;
    }
    __syncthreads();

    float h[4][16];
    #pragma unroll
    for (int q = 0; q < 4; ++q)
        #pragma unroll
        for (int k = 0; k < 16; ++k) h[q][k] = 0.f;

    int p = tid;
    #pragma unroll
    for (int q = 0; q < 4; ++q) {
        const __hip_bfloat16* base =
            l2 + ((size_t)tb * 1024 + q * 256 + cg * 16) * 256 + p;
        #pragma unroll
        for (int d = 0; d < 16; ++d) {
            float xv = bf2f(base[d * 256]) * bsc[q * 16 + d] + bsh[q * 16 + d];
            #pragma unroll
            for (int k = 0; k < 16; ++k)
                h[q][k] = fmaf(xv, wt[q][d][k], h[q][k]);
        }
    }

    int uh = tid >> 4, uw = tid & 15;
    __hip_bfloat16* ob = rec + ((size_t)tb * 256 + cg * 16) * 1024;
    #pragma unroll
    for (int k = 0; k < 16; ++k) {
        float LL = h[0][k], HL = h[1][k], LH = h[2][k], HH = h[3][k];
        float v00 = 0.5f * (LL + HL + LH + HH);
        float v01 = 0.5f * (LL + HL - LH - HH);
        float v10 = 0.5f * (LL - HL + LH - HH);
        float v11 = 0.5f * (LL - HL - LH + HH);
        __hip_bfloat162 top, bot;
        top.x = __float2bfloat16(v00); top.y = __float2bfloat16(v01);
        bot.x = __float2bfloat16(v10); bot.y = __float2bfloat16(v11);
        *(__hip_bfloat162*)(ob + (size_t)k * 1024 + (2 * uh) * 32 + 2 * uw) = top;
        *(__hip_bfloat162*)(ob + (size_t)k * 1024 + (2 * uh + 1) * 32 + 2 * uw) = bot;
    }
}

// ---------------------------------------------------------------------------
// Grouped 1x1 + 3x3 convs, LDS-staged fp32 tile (zero-padded halo).
// Block = (image, 8-row strip); thread = pixel in strip.
// ---------------------------------------------------------------------------
__global__ __launch_bounds__(256) void k_conv(const unsigned char* __restrict__ s,
                                              const __hip_bfloat16* __restrict__ wc,
                                              __hip_bfloat16* __restrict__ c1,
                                              __hip_bfloat16* __restrict__ c2) {
    int bid = blockIdx.x;                 // 1024 = img(256) * strip(4)
    int img = bid >> 2;
    int strip = bid & 3;
    int tid = threadIdx.x;

    __shared__ float tile[16 * 10 * 36];  // [d][row 0..9][col 0..35], fp32
    __shared__ float W1s[16][16];         // [k][d]
    __shared__ float W2s[16][144];        // [k][d*9+tap]
    __shared__ float B1s[16], B2s[16];

    W1s[tid >> 4][tid & 15] = bf2f(wc[OFF_W1 + tid]);
    for (int i = tid; i < 2304; i += 256)
        W2s[i / 144][i % 144] = bf2f(wc[OFF_W2 + i]);
    if (tid < 16) {
        B1s[tid] = bf2f(wc[OFF_B1 + tid]);
        B2s[tid] = bf2f(wc[OFF_B2 + tid]);
    }
    const unsigned char* sb = s + (size_t)img * 16384;
    for (int i = tid; i < 5760; i += 256) {
        int d = i / 360;
        int rem = i - d * 360;
        int r = rem / 36;
        int cc = rem - r * 36;
        float v = 0.f;
        if (cc < 34) {
            int gh = strip * 8 + r - 1;
            int gw = cc - 1;
            if (gh >= 0 && gh < 32 && gw >= 0 && gw < 32)
                v = (float)sb[d * 1024 + gh * 32 + gw];
        }
        tile[i] = v;
    }
    __syncthreads();

    int hl = tid >> 5, w = tid & 31;
    float a1[16], a2[16];
    #pragma unroll
    for (int k = 0; k < 16; ++k) { a1[k] = B1s[k]; a2[k] = B2s[k]; }

    for (int d = 0; d < 16; ++d) {
        const float* tp = tile + d * 360 + hl * 36 + w;
        float t0 = tp[0],  t1 = tp[1],  t2 = tp[2];
        float t3 = tp[36], t4 = tp[37], t5 = tp[38];
        float t6 = tp[72], t7 = tp[73], t8 = tp[74];
        #pragma unroll
        for (int k = 0; k < 16; ++k) {
            a1[k] = fmaf(W1s[k][d], t4, a1[k]);
            const float* wk = &W2s[k][d * 9];
            float acc = a2[k];
            acc = fmaf(wk[0], t0, acc); acc = fmaf(wk[1], t1, acc);
            acc = fmaf(wk[2], t2, acc); acc = fmaf(wk[3], t3, acc);
            acc = fmaf(wk[4], t4, acc); acc = fmaf(wk[5], t5, acc);
            acc = fmaf(wk[6], t6, acc); acc = fmaf(wk[7], t7, acc);
            acc = fmaf(wk[8], t8, acc);
            a2[k] = acc;
        }
    }
    int pix = (strip * 8 + hl) * 32 + w;
    __hip_bfloat16* o1 = c1 + (size_t)img * 16384;
    __hip_bfloat16* o2 = c2 + (size_t)img * 16384;
    #pragma unroll
    for (int k = 0; k < 16; ++k) {
        o1[k * 1024 + pix] = __float2bfloat16(a1[k]);
        o2[k * 1024 + pix] = __float2bfloat16(a2[k]);
    }
}

// ---------------------------------------------------------------------------
// Combined BN3/4/5 stats: 768 blocks = which(3) * channel(256).
// Writes scale/shift directly into stats[3072 + which*512 + {c, 256+c}].
// ---------------------------------------------------------------------------
__global__ __launch_bounds__(256) void k_stats3(const __hip_bfloat16* __restrict__ rec,
                                                const __hip_bfloat16* __restrict__ c1,
                                                const __hip_bfloat16* __restrict__ c2,
                                                const __hip_bfloat16* __restrict__ wc,
                                                float* __restrict__ stats) {
    int bid = blockIdx.x;
    int which = bid >> 8;
    int c = bid & 255;
    int tid = threadIdx.x;
    const __hip_bfloat16* buf = (which == 0) ? rec : ((which == 1) ? c1 : c2);

    float sum = 0.f, ss = 0.f;
    for (int tb = 0; tb < TB_; ++tb) {
        const __hip_bfloat162* p =
            (const __hip_bfloat162*)(buf + ((size_t)tb * 256 + c) * 1024);
        for (int j = tid; j < 512; j += 256) {
            __hip_bfloat162 v = p[j];
            float f0 = bf2f(v.x), f1 = bf2f(v.y);
            sum += f0 + f1;
            ss += f0 * f0 + f1 * f1;
        }
    }
    __shared__ float rs[256], rq[256];
    rs[tid] = sum; rq[tid] = ss;
    __syncthreads();
    for (int o = 128; o > 0; o >>= 1) {
        if (tid < o) { rs[tid] += rs[tid + o]; rq[tid] += rq[tid + o]; }
        __syncthreads();
    }
    if (tid == 0) {
        float n = 16384.f;
        float m = rs[0] / n;
        float var = fmaxf(rq[0] / n - m * m, 0.f);
        float sc = bf2f(wc[OFF_G3 + which * 512 + c]) * rsqrtf(var + EPSBN);
        stats[3072 + which * 512 + c] = sc;
        stats[3072 + which * 512 + 256 + c] = bf2f(wc[OFF_G3 + which * 512 + 256 + c]) - m * sc;
    }
}

// ---------------------------------------------------------------------------
// Final combine (2 elems/thread): out = bn3(rec)+bn4(c1)+bn5(c2).
// ---------------------------------------------------------------------------
__global__ __launch_bounds__(256) void k_final(const __hip_bfloat16* __restrict__ rec,
                                               const __hip_bfloat16* __restrict__ c1,
                                               const __hip_bfloat16* __restrict__ c2,
                                               const float* __restrict__ stats,
                                               const int* __restrict__ flag,
                                               void* __restrict__ out_) {
    int n2 = blockIdx.x * 256 + threadIdx.x;    // 2,097,152
    int c = ((n2 * 2) >> 10) & 255;
    float sc3 = stats[3072 + c],        sh3 = stats[3328 + c];
    float sc4 = stats[3584 + c],        sh4 = stats[3840 + c];
    float sc5 = stats[4096 + c],        sh5 = stats[4352 + c];
    __hip_bfloat162 r = ((const __hip_bfloat162*)rec)[n2];
    __hip_bfloat162 a = ((const __hip_bfloat162*)c1)[n2];
    __hip_bfloat162 b = ((const __hip_bfloat162*)c2)[n2];
    float v0 = bf2f(r.x) * sc3 + sh3 + bf2f(a.x) * sc4 + sh4 + bf2f(b.x) * sc5 + sh5;
    float v1 = bf2f(r.y) * sc3 + sh3 + bf2f(a.y) * sc4 + sh4 + bf2f(b.y) * sc5 + sh5;
    if (*flag) {
        ((float2*)out_)[n2] = make_float2(v0, v1);
    } else {
        __hip_bfloat162 o;
        o.x = __float2bfloat16(v0); o.y = __float2bfloat16(v1);
        ((__hip_bfloat162*)out_)[n2] = o;
    }
}

// ---------------------------------------------------------------------------
extern "C" void kernel_launch(void* const* d_in, const int* in_sizes, int n_in,
                              void* d_out, int out_size, void* d_ws, size_t ws_size,
                              hipStream_t stream) {
    char* ws = (char*)d_ws;
    unsigned char* s_u8  = (unsigned char*)ws;                          // [0,4M)
    signed char* l1c     = (signed char*)(ws + ((size_t)4 << 20));      // [4,8M)
    __hip_bfloat16* l2   = (__hip_bfloat16*)(ws + ((size_t)8 << 20));   // [8,16M) -> reused as c1
    __hip_bfloat16* c1   = (__hip_bfloat16*)(ws + ((size_t)8 << 20));
    __hip_bfloat16* rec  = (__hip_bfloat16*)(ws + ((size_t)16 << 20));  // [16,24M)
    __hip_bfloat16* c2   = (__hip_bfloat16*)(ws + ((size_t)24 << 20));  // [24,32M)
    __hip_bfloat16* wc   = (__hip_bfloat16*)(ws + ((size_t)32 << 20));
    float* stats         = (float*)(ws + ((size_t)32 << 20) + (64 << 10));
    int* flag            = (int*)(ws + ((size_t)32 << 20) + (128 << 10));

    float* sums1 = stats;            // 1024 floats
    float* sums2 = stats + 1024;     // 2048 floats

    WPtrs wp;
    for (int i = 0; i < 15; ++i) wp.p[i] = d_in[i + 1];

    dim3 blk(256);
    k_sniff<<<dim3(1), blk, 0, stream>>>((const unsigned short*)d_in[0], flag);
    k_convert<<<dim3(57), blk, 0, stream>>>(wp, wc, stats, flag);
    k_lifhaar<<<dim3(2048), blk, 0, stream>>>(d_in[0], flag, s_u8, l1c, sums1);
    k_stage2<<<dim3(4096), blk, 0, stream>>>(l1c, sums1, wc, sums2, l2);
    k_mixinv<<<dim3(256), blk, 0, stream>>>(l2, sums2, wc, rec);
    k_conv<<<dim3(1024), blk, 0, stream>>>(s_u8, wc, c1, c2);
    k_stats3<<<dim3(768), blk, 0, stream>>>(rec, c1, c2, wc, stats);
    k_final<<<dim3(8192), blk, 0, stream>>>(rec, c1, c2, stats, flag, d_out);
}

// Round 4
// 183.535 us; speedup vs baseline: 1.4304x; 1.1324x over previous
//
#include <hip/hip_runtime.h>
#include <hip/hip_bf16.h>

#define T_ 4
#define B_ 4
#define C_ 256
#define H_ 32
#define W_ 32
#define TB_ 16
#define Hh_ 16
#define Wh_ 16
#define INVS2 0.70710678118654752440f
#define EPSBN 1e-5f

// Canonical weight arena offsets (bf16 elements)
#define OFF_HW   0
#define OFF_W1   4096
#define OFF_B1   4352
#define OFF_W2   4368
#define OFF_B2   6672
#define OFF_G1   6688
#define OFF_BE1  7200
#define OFF_G2   7712
#define OFF_BE2  8736
#define OFF_G3   9760
#define OFF_BE3  10016
#define OFF_G4   10272
#define OFF_BE4  10528
#define OFF_G5   10784
#define OFF_BE5  11040
#define W_TOTAL  11296
#define NSUMS    3072          // raw sums: BN1 (1024) + BN2 (2048)

struct WPtrs { const void* p[15]; };

typedef __attribute__((ext_vector_type(8))) short short8;
typedef __attribute__((ext_vector_type(4))) float f32x4;

__device__ inline float bf2f(__hip_bfloat16 v) { return __bfloat162float(v); }
__device__ inline float bfu(unsigned short u) { return __uint_as_float((unsigned)u << 16); }

// ---------------------------------------------------------------------------
// Dtype sniff: inputs fp32 (flag=1) or bf16 (flag=0).
// ---------------------------------------------------------------------------
__global__ __launch_bounds__(256) void k_sniff(const unsigned short* __restrict__ xr,
                                               int* __restrict__ flag) {
    int tid = threadIdx.x;
    int cnt = 0;
    for (int i = tid; i < 2048; i += 256) {
        int e = (xr[i] >> 7) & 0xFF;
        if (e >= 134) cnt++;
    }
    for (int o = 1; o < 64; o <<= 1) cnt += __shfl_xor(cnt, o, 64);
    __shared__ int sh[4];
    if ((tid & 63) == 0) sh[tid >> 6] = cnt;
    __syncthreads();
    if (tid == 0) *flag = (sh[0] + sh[1] + sh[2] + sh[3] >= 32) ? 1 : 0;
}

// ---------------------------------------------------------------------------
// Canonicalize weights to bf16 arena + zero the raw-sums region.
// ---------------------------------------------------------------------------
__global__ __launch_bounds__(256) void k_convert(WPtrs wp,
                                                 __hip_bfloat16* __restrict__ wc,
                                                 float* __restrict__ sums,
                                                 const int* __restrict__ flag) {
    const int sizes[15] = {4096, 256, 16, 2304, 16, 512, 512, 1024, 1024,
                           256, 256, 256, 256, 256, 256};
    int f = *flag;
    int i = blockIdx.x * 256 + threadIdx.x;
    if (i < W_TOTAL) {
        int seg = 0, off = 0;
        while (i >= off + sizes[seg]) { off += sizes[seg]; seg++; }
        int j = i - off;
        float v = f ? ((const float*)wp.p[seg])[j]
                    : bf2f(((const __hip_bfloat16*)wp.p[seg])[j]);
        wc[i] = __float2bfloat16(v);
    }
    int z = i - W_TOTAL;
    if (z >= 0 && z < NSUMS) sums[z] = 0.f;
}

// ---------------------------------------------------------------------------
// Fused LIF + Haar-W. Thread = (b, c, h, w-pair), loops t.
// Writes channel-last bf16 spikes s_cl[img][h][w][d] (img=tb*16+c/16, d=c%16)
// + i8 Haar codes; accumulates BN1 raw sums via butterfly + atomics.
// ---------------------------------------------------------------------------
__global__ __launch_bounds__(256) void k_lifhaar(const void* __restrict__ x_,
                                                 const int* __restrict__ flag,
                                                 unsigned short* __restrict__ s_cl,
                                                 signed char* __restrict__ l1,
                                                 float* __restrict__ sums1) {
    int bid = blockIdx.x;                      // 2048 = b(4) * c(256) * half(2)
    int tid = threadIdx.x;
    int half = bid & 1;
    int c = (bid >> 1) & 255;
    int b = bid >> 9;
    int wp = tid & 15;
    int hl = tid >> 4;
    int h = half * 16 + hl;
    int f = *flag;
    const float* xf = (const float*)x_;
    const unsigned int* xb = (const unsigned int*)x_;
    int n = ((b * 256 + c) * 32 + h) * 32 + 2 * wp;
    int d = c & 15, nb = c >> 4;

    float v0 = 0.f, v1 = 0.f;
    float aL = 0.f, qL = 0.f, aH = 0.f, qH = 0.f;
    #pragma unroll
    for (int t = 0; t < T_; ++t) {
        size_t idx = (size_t)t * 1048576 + n;
        float x0, x1;
        if (f) {
            float2 xx = *(const float2*)(xf + idx);
            x0 = xx.x; x1 = xx.y;
        } else {
            unsigned int u = xb[idx >> 1];
            x0 = __uint_as_float(u << 16);
            x1 = __uint_as_float(u & 0xffff0000u);
        }
        v0 += (x0 - v0) * 0.5f;
        v1 += (x1 - v1) * 0.5f;
        float s0 = (v0 >= 1.f) ? 1.f : 0.f;
        float s1 = (v1 >= 1.f) ? 1.f : 0.f;
        v0 *= (1.f - s0);
        v1 *= (1.f - s1);
        int tb = t * 4 + b;
        // channel-last spike store (bf16 bit patterns, exact)
        int img = tb * 16 + nb;
        size_t sb = ((size_t)img * 1024 + h * 32 + 2 * wp) * 16 + d;
        s_cl[sb]      = s0 ? 0x3F80 : 0;
        s_cl[sb + 16] = s1 ? 0x3F80 : 0;
        float cl = s0 + s1, ch = s0 - s1;
        size_t lb = (((size_t)tb * 512 + c) * 32 + h) * 16 + wp;
        l1[lb] = (signed char)(int)cl;
        l1[lb + (size_t)256 * 512] = (signed char)(int)ch;
        aL += cl; qL += cl * cl; aH += ch; qH += ch * ch;
    }
    for (int o = 1; o < 64; o <<= 1) {
        aL += __shfl_xor(aL, o, 64); qL += __shfl_xor(qL, o, 64);
        aH += __shfl_xor(aH, o, 64); qH += __shfl_xor(qH, o, 64);
    }
    __shared__ float part[4][4];
    int lane = tid & 63, wv = tid >> 6;
    if (lane == 0) {
        part[wv][0] = aL; part[wv][1] = qL; part[wv][2] = aH; part[wv][3] = qH;
    }
    __syncthreads();
    if (tid < 4) {
        float tot = part[0][tid] + part[1][tid] + part[2][tid] + part[3][tid];
        const int offs[4] = {0, 512, 256, 768};
        atomicAdd(&sums1[offs[tid] + c], tot);
    }
}

// ---------------------------------------------------------------------------
// BN1-apply + Haar-H + elementwise gate + energy gate -> l2 bf16;
// accumulates BN2 raw sums. Butterfly reductions, 2 barriers.
// ---------------------------------------------------------------------------
__global__ __launch_bounds__(256) void k_stage2(const signed char* __restrict__ l1,
                                                const float* __restrict__ sums1,
                                                const __hip_bfloat16* __restrict__ wc,
                                                float* __restrict__ sums2,
                                                __hip_bfloat16* __restrict__ l2) {
    int blk = blockIdx.x;                 // TB*C = 4096
    int c = blk & 255;
    int tb = blk >> 8;
    int tid = threadIdx.x;
    int lane = tid & 63, wv = tid >> 6;

    const float nrm = 1.f / 8192.f;
    float mL = sums1[c] * INVS2 * nrm;
    float vL = fmaxf(sums1[512 + c] * 0.5f * nrm - mL * mL, 0.f);
    float sL = bf2f(wc[OFF_G1 + c]) * rsqrtf(vL + EPSBN);
    float tL = bf2f(wc[OFF_BE1 + c]) - mL * sL;
    float mH = sums1[256 + c] * INVS2 * nrm;
    float vH = fmaxf(sums1[768 + c] * 0.5f * nrm - mH * mH, 0.f);
    float sH = bf2f(wc[OFF_G1 + 256 + c]) * rsqrtf(vH + EPSBN);
    float tH = bf2f(wc[OFF_BE1 + 256 + c]) - mH * sH;

    __shared__ float lo[H_ * Wh_];
    __shared__ float hi[H_ * Wh_];
    const signed char* plo = l1 + (((size_t)tb * 512) + c) * (H_ * Wh_);
    const signed char* phi = l1 + (((size_t)tb * 512) + 256 + c) * (H_ * Wh_);
    float slo = sL * INVS2, shi = sH * INVS2;
    {
        float a = (float)plo[tid] * slo + tL;
        float b = (float)phi[tid] * shi + tH;
        lo[tid] = a; hi[tid] = b;
        a = (float)plo[tid + 256] * slo + tL;
        b = (float)phi[tid + 256] * shi + tH;
        lo[tid + 256] = a; hi[tid + 256] = b;
    }
    __syncthreads();

    int w = tid & 15, v = tid >> 4;
    float a = lo[(2 * v) * Wh_ + w], b = lo[(2 * v + 1) * Wh_ + w];
    float zLL = (a + b) * INVS2;
    float zHL = (a - b) * INVS2;
    a = hi[(2 * v) * Wh_ + w]; b = hi[(2 * v + 1) * Wh_ + w];
    float zLH = (a + b) * INVS2;
    float zHH = (a - b) * INVS2;
    zLL = (fabsf(zLL) - 0.5f >= 0.f) ? zLL : 0.f;
    zHL = (fabsf(zHL) - 0.5f >= 0.f) ? zHL : 0.f;
    zLH = (fabsf(zLH) - 0.5f >= 0.f) ? zLH : 0.f;
    zHH = (fabsf(zHH) - 0.5f >= 0.f) ? zHH : 0.f;

    float r0 = zLL, r1 = zHL, r2 = zLH, r3 = zHH;
    float q0 = zLL * zLL, q1 = zHL * zHL, q2 = zLH * zLH, q3 = zHH * zHH;
    for (int o = 1; o < 64; o <<= 1) {
        r0 += __shfl_xor(r0, o, 64); r1 += __shfl_xor(r1, o, 64);
        r2 += __shfl_xor(r2, o, 64); r3 += __shfl_xor(r3, o, 64);
        q0 += __shfl_xor(q0, o, 64); q1 += __shfl_xor(q1, o, 64);
        q2 += __shfl_xor(q2, o, 64); q3 += __shfl_xor(q3, o, 64);
    }
    __shared__ float part[4][8];
    if (lane == 0) {
        part[wv][0] = r0; part[wv][1] = r1; part[wv][2] = r2; part[wv][3] = r3;
        part[wv][4] = q0; part[wv][5] = q1; part[wv][6] = q2; part[wv][7] = q3;
    }
    __syncthreads();
    float S0 = part[0][0] + part[1][0] + part[2][0] + part[3][0];
    float S1 = part[0][1] + part[1][1] + part[2][1] + part[3][1];
    float S2 = part[0][2] + part[1][2] + part[2][2] + part[3][2];
    float S3 = part[0][3] + part[1][3] + part[2][3] + part[3][3];
    float Q0 = part[0][4] + part[1][4] + part[2][4] + part[3][4];
    float Q1 = part[0][5] + part[1][5] + part[2][5] + part[3][5];
    float Q2 = part[0][6] + part[1][6] + part[2][6] + part[3][6];
    float Q3 = part[0][7] + part[1][7] + part[2][7] + part[3][7];
    float fLL = (Q0 * (1.f / 256.f) > 0.01f) ? 1.f : 0.f;
    float fHL = (Q1 * (1.f / 256.f) > 0.02f) ? 1.f : 0.f;
    float fLH = (Q2 * (1.f / 256.f) > 0.02f) ? 1.f : 0.f;
    float fHH = (Q3 * (1.f / 256.f) > 0.05f) ? 1.f : 0.f;

    if (tid < 8) {
        const int cho[8] = {0, 1024, 256, 1280, 512, 1536, 768, 1792};
        const float vals[8] = {fLL * S0, fLL * Q0, fHL * S1, fHL * Q1,
                               fLH * S2, fLH * Q2, fHH * S3, fHH * Q3};
        atomicAdd(&sums2[cho[tid] + c], vals[tid]);
    }

    size_t ob = (((size_t)tb * 1024) + c) * 256 + tid;
    l2[ob]               = __float2bfloat16(zLL * fLL);
    l2[ob + 256u * 256u] = __float2bfloat16(zHL * fHL);
    l2[ob + 512u * 256u] = __float2bfloat16(zLH * fLH);
    l2[ob + 768u * 256u] = __float2bfloat16(zHH * fHH);
}

// ---------------------------------------------------------------------------
// Fused BN2-apply + block channel matmul + inverse Haar -> rec bf16.
// ---------------------------------------------------------------------------
__global__ __launch_bounds__(256) void k_mixinv(const __hip_bfloat16* __restrict__ l2,
                                                const float* __restrict__ sums2,
                                                const __hip_bfloat16* __restrict__ wc,
                                                __hip_bfloat16* __restrict__ rec) {
    int bid = blockIdx.x;                 // 256 = tb(16) * cg(16)
    int cg = bid & 15;
    int tb = bid >> 4;
    int tid = threadIdx.x;

    __shared__ float wt[4][16][16];       // [q][d][k]
    __shared__ float bsc[64], bsh[64];
    for (int i = tid; i < 1024; i += 256) {
        int q = i >> 8, rem = i & 255, d = rem >> 4, k = rem & 15;
        int nb = q * 4 + (cg >> 2);
        wt[q][d][k] = bf2f(wc[OFF_HW + nb * 256 + d * 16 + k]);
    }
    if (tid < 64) {
        int q = tid >> 4, d = tid & 15;
        int ch = q * 256 + cg * 16 + d;
        float m = sums2[ch] * (1.f / 4096.f);
        float var = fmaxf(sums2[1024 + ch] * (1.f / 4096.f) - m * m, 0.f);
        float sc = bf2f(wc[OFF_G2 + ch]) * rsqrtf(var + EPSBN);
        bsc[tid] = sc;
        bsh[tid] = bf2f(wc[OFF_BE2 + ch]) - m * sc;
    }
    __syncthreads();

    float h[4][16];
    #pragma unroll
    for (int q = 0; q < 4; ++q)
        #pragma unroll
        for (int k = 0; k < 16; ++k) h[q][k] = 0.f;

    int p = tid;
    #pragma unroll
    for (int q = 0; q < 4; ++q) {
        const __hip_bfloat16* base =
            l2 + ((size_t)tb * 1024 + q * 256 + cg * 16) * 256 + p;
        #pragma unroll
        for (int d = 0; d < 16; ++d) {
            float xv = bf2f(base[d * 256]) * bsc[q * 16 + d] + bsh[q * 16 + d];
            #pragma unroll
            for (int k = 0; k < 16; ++k)
                h[q][k] = fmaf(xv, wt[q][d][k], h[q][k]);
        }
    }

    int uh = tid >> 4, uw = tid & 15;
    __hip_bfloat16* ob = rec + ((size_t)tb * 256 + cg * 16) * 1024;
    #pragma unroll
    for (int k = 0; k < 16; ++k) {
        float LL = h[0][k], HL = h[1][k], LH = h[2][k], HH = h[3][k];
        float v00 = 0.5f * (LL + HL + LH + HH);
        float v01 = 0.5f * (LL + HL - LH - HH);
        float v10 = 0.5f * (LL - HL + LH - HH);
        float v11 = 0.5f * (LL - HL - LH + HH);
        __hip_bfloat162 top, bot;
        top.x = __float2bfloat16(v00); top.y = __float2bfloat16(v01);
        bot.x = __float2bfloat16(v10); bot.y = __float2bfloat16(v11);
        *(__hip_bfloat162*)(ob + (size_t)k * 1024 + (2 * uh) * 32 + 2 * uw) = top;
        *(__hip_bfloat162*)(ob + (size_t)k * 1024 + (2 * uh + 1) * 32 + 2 * uw) = bot;
    }
}

// ---------------------------------------------------------------------------
// Grouped 1x1 + 3x3 convs via MFMA implicit GEMM.
// Block = image (256 blocks, 4 waves). Wave handles 16 tiles of
// (row h, 16 cols). D[k_out][pix] = sum_{tap,d} W[k_out][tap*16+d]*s_shift.
// Taps paired 2-per-MFMA (K=32); 1x1 conv reuses center-tap B-frag.
// ---------------------------------------------------------------------------
__global__ __launch_bounds__(256) void k_conv(const unsigned short* __restrict__ s_cl,
                                              const __hip_bfloat16* __restrict__ wc,
                                              __hip_bfloat16* __restrict__ c1,
                                              __hip_bfloat16* __restrict__ c2) {
    int img = blockIdx.x;                 // 256
    int tid = threadIdx.x;
    int lane = tid & 63;
    int wv = tid >> 6;

    __shared__ unsigned short w2s[2304];  // [k_out][d*9+tap]
    __shared__ unsigned short w1s[256];   // [k_out][d]
    __shared__ unsigned short bs[32];     // B1 | B2
    const unsigned short* wr = (const unsigned short*)wc;
    for (int i = tid; i < 2304; i += 256) w2s[i] = wr[OFF_W2 + i];
    w1s[tid] = wr[OFF_W1 + tid];
    if (tid < 16) { bs[tid] = wr[OFF_B1 + tid]; bs[16 + tid] = wr[OFF_B2 + tid]; }
    __syncthreads();

    int m = lane & 15;                    // k_out for A; pixel n for B/C
    int g = lane >> 4;
    const int tapA[5] = {0, 2, 4, 6, 8};
    const int tapB[5] = {1, 3, 5, 7, 8};  // p4 second half: zero A

    short8 afr[5], a1f;
    #pragma unroll
    for (int p = 0; p < 5; ++p) {
        int tap = (g < 2) ? tapA[p] : tapB[p];
        short8 av;
        #pragma unroll
        for (int j = 0; j < 8; ++j) {
            int d = (g & 1) * 8 + j;
            unsigned short w = w2s[m * 144 + d * 9 + tap];
            if (p == 4 && g >= 2) w = 0;
            av[j] = (short)w;
        }
        afr[p] = av;
    }
    #pragma unroll
    for (int j = 0; j < 8; ++j) {
        int d = (g & 1) * 8 + j;
        a1f[j] = (g < 2) ? (short)w1s[m * 16 + d] : (short)0;
    }

    float bias1[4], bias2[4];
    #pragma unroll
    for (int r = 0; r < 4; ++r) {
        bias1[r] = bfu(bs[g * 4 + r]);
        bias2[r] = bfu(bs[16 + g * 4 + r]);
    }

    const unsigned short* sb = s_cl + (size_t)img * 16384;
    __hip_bfloat16* o1 = c1 + (size_t)img * 16384;
    __hip_bfloat16* o2 = c2 + (size_t)img * 16384;

    for (int t = wv * 16; t < wv * 16 + 16; ++t) {
        int h = t >> 1;
        int w0 = (t & 1) << 4;
        f32x4 acc2 = {0.f, 0.f, 0.f, 0.f};
        f32x4 acc1 = {0.f, 0.f, 0.f, 0.f};
        #pragma unroll
        for (int p = 0; p < 5; ++p) {
            int tap = (g < 2) ? tapA[p] : tapB[p];
            int row = h + tap / 3 - 1;
            int col = w0 + m + (tap % 3) - 1;
            bool ok = ((unsigned)row < 32u) && ((unsigned)col < 32u);
            int rr = ok ? row : 0, cc = ok ? col : 0;
            const short8* bp = (const short8*)(sb + ((size_t)(rr * 32 + cc)) * 16 + (g & 1) * 8);
            short8 bv = *bp;
            if (!ok) bv = (short8)0;
            acc2 = __builtin_amdgcn_mfma_f32_16x16x32_bf16(afr[p], bv, acc2, 0, 0, 0);
            if (p == 2)
                acc1 = __builtin_amdgcn_mfma_f32_16x16x32_bf16(a1f, bv, acc1, 0, 0, 0);
        }
        int pix = h * 32 + w0 + m;        // C col = lane&15
        #pragma unroll
        for (int r = 0; r < 4; ++r) {
            int k = g * 4 + r;            // C row = (lane>>4)*4 + r
            o1[(size_t)k * 1024 + pix] = __float2bfloat16(acc1[r] + bias1[r]);
            o2[(size_t)k * 1024 + pix] = __float2bfloat16(acc2[r] + bias2[r]);
        }
    }
}

// ---------------------------------------------------------------------------
// Combined BN3/4/5 stats: 768 blocks = which(3) * channel(256).
// ---------------------------------------------------------------------------
__global__ __launch_bounds__(256) void k_stats3(const __hip_bfloat16* __restrict__ rec,
                                                const __hip_bfloat16* __restrict__ c1,
                                                const __hip_bfloat16* __restrict__ c2,
                                                const __hip_bfloat16* __restrict__ wc,
                                                float* __restrict__ stats) {
    int bid = blockIdx.x;
    int which = bid >> 8;
    int c = bid & 255;
    int tid = threadIdx.x;
    const __hip_bfloat16* buf = (which == 0) ? rec : ((which == 1) ? c1 : c2);

    float sum = 0.f, ss = 0.f;
    for (int tb = 0; tb < TB_; ++tb) {
        const __hip_bfloat162* p =
            (const __hip_bfloat162*)(buf + ((size_t)tb * 256 + c) * 1024);
        for (int j = tid; j < 512; j += 256) {
            __hip_bfloat162 v = p[j];
            float f0 = bf2f(v.x), f1 = bf2f(v.y);
            sum += f0 + f1;
            ss += f0 * f0 + f1 * f1;
        }
    }
    for (int o = 1; o < 64; o <<= 1) {
        sum += __shfl_xor(sum, o, 64);
        ss  += __shfl_xor(ss, o, 64);
    }
    __shared__ float part[4][2];
    int lane = tid & 63, wv = tid >> 6;
    if (lane == 0) { part[wv][0] = sum; part[wv][1] = ss; }
    __syncthreads();
    if (tid == 0) {
        float S = part[0][0] + part[1][0] + part[2][0] + part[3][0];
        float Q = part[0][1] + part[1][1] + part[2][1] + part[3][1];
        float n = 16384.f;
        float m = S / n;
        float var = fmaxf(Q / n - m * m, 0.f);
        float sc = bf2f(wc[OFF_G3 + which * 512 + c]) * rsqrtf(var + EPSBN);
        stats[3072 + which * 512 + c] = sc;
        stats[3072 + which * 512 + 256 + c] =
            bf2f(wc[OFF_G3 + which * 512 + 256 + c]) - m * sc;
    }
}

// ---------------------------------------------------------------------------
// Final combine (2 elems/thread): out = bn3(rec)+bn4(c1)+bn5(c2).
// ---------------------------------------------------------------------------
__global__ __launch_bounds__(256) void k_final(const __hip_bfloat16* __restrict__ rec,
                                               const __hip_bfloat16* __restrict__ c1,
                                               const __hip_bfloat16* __restrict__ c2,
                                               const float* __restrict__ stats,
                                               const int* __restrict__ flag,
                                               void* __restrict__ out_) {
    int n2 = blockIdx.x * 256 + threadIdx.x;    // 2,097,152
    int c = ((n2 * 2) >> 10) & 255;
    float sc3 = stats[3072 + c],        sh3 = stats[3328 + c];
    float sc4 = stats[3584 + c],        sh4 = stats[3840 + c];
    float sc5 = stats[4096 + c],        sh5 = stats[4352 + c];
    __hip_bfloat162 r = ((const __hip_bfloat162*)rec)[n2];
    __hip_bfloat162 a = ((const __hip_bfloat162*)c1)[n2];
    __hip_bfloat162 b = ((const __hip_bfloat162*)c2)[n2];
    float v0 = bf2f(r.x) * sc3 + sh3 + bf2f(a.x) * sc4 + sh4 + bf2f(b.x) * sc5 + sh5;
    float v1 = bf2f(r.y) * sc3 + sh3 + bf2f(a.y) * sc4 + sh4 + bf2f(b.y) * sc5 + sh5;
    if (*flag) {
        ((float2*)out_)[n2] = make_float2(v0, v1);
    } else {
        __hip_bfloat162 o;
        o.x = __float2bfloat16(v0); o.y = __float2bfloat16(v1);
        ((__hip_bfloat162*)out_)[n2] = o;
    }
}

// ---------------------------------------------------------------------------
// Workspace map (peak 32.13 MB — proven safe in R2/R3):
//   [0,8M):   s_cl (bf16 channel-last spikes)
//   [8,16M):  l2  -> c1 (l2 dead after k_mixinv)
//   [16,24M): rec
//   [24,28M): l1c (dead after k_stage2)
//   [24,32M): c2 (overlays dead l1c)
//   [32M..):  weight arena, stats, flag
// Order: sniff, convert, lifhaar, stage2, mixinv, conv, stats3, final.
// ---------------------------------------------------------------------------
extern "C" void kernel_launch(void* const* d_in, const int* in_sizes, int n_in,
                              void* d_out, int out_size, void* d_ws, size_t ws_size,
                              hipStream_t stream) {
    char* ws = (char*)d_ws;
    unsigned short* s_cl = (unsigned short*)ws;
    __hip_bfloat16* l2   = (__hip_bfloat16*)(ws + ((size_t)8 << 20));
    __hip_bfloat16* c1   = (__hip_bfloat16*)(ws + ((size_t)8 << 20));
    __hip_bfloat16* rec  = (__hip_bfloat16*)(ws + ((size_t)16 << 20));
    signed char* l1c     = (signed char*)(ws + ((size_t)24 << 20));
    __hip_bfloat16* c2   = (__hip_bfloat16*)(ws + ((size_t)24 << 20));
    __hip_bfloat16* wc   = (__hip_bfloat16*)(ws + ((size_t)32 << 20));
    float* stats         = (float*)(ws + ((size_t)32 << 20) + (64 << 10));
    int* flag            = (int*)(ws + ((size_t)32 << 20) + (128 << 10));

    float* sums1 = stats;            // 1024 floats
    float* sums2 = stats + 1024;     // 2048 floats

    WPtrs wp;
    for (int i = 0; i < 15; ++i) wp.p[i] = d_in[i + 1];

    dim3 blk(256);
    k_sniff<<<dim3(1), blk, 0, stream>>>((const unsigned short*)d_in[0], flag);
    k_convert<<<dim3(57), blk, 0, stream>>>(wp, wc, stats, flag);
    k_lifhaar<<<dim3(2048), blk, 0, stream>>>(d_in[0], flag, s_cl, l1c, sums1);
    k_stage2<<<dim3(4096), blk, 0, stream>>>(l1c, sums1, wc, sums2, l2);
    k_mixinv<<<dim3(256), blk, 0, stream>>>(l2, sums2, wc, rec);
    k_conv<<<dim3(256), blk, 0, stream>>>(s_cl, wc, c1, c2);
    k_stats3<<<dim3(768), blk, 0, stream>>>(rec, c1, c2, wc, stats);
    k_final<<<dim3(8192), blk, 0, stream>>>(rec, c1, c2, stats, flag, d_out);
}

// Round 5
// 148.423 us; speedup vs baseline: 1.7688x; 1.2366x over previous
//
#include <hip/hip_runtime.h>
#include <hip/hip_bf16.h>

#define T_ 4
#define B_ 4
#define C_ 256
#define H_ 32
#define W_ 32
#define TB_ 16
#define Hh_ 16
#define Wh_ 16
#define INVS2 0.70710678118654752440f
#define EPSBN 1e-5f

// Canonical weight arena offsets (bf16 elements)
#define OFF_HW   0
#define OFF_W1   4096
#define OFF_B1   4352
#define OFF_W2   4368
#define OFF_B2   6672
#define OFF_G1   6688
#define OFF_BE1  7200
#define OFF_G2   7712
#define OFF_BE2  8736
#define OFF_G3   9760
#define OFF_BE3  10016
#define OFF_G4   10272
#define OFF_BE4  10528
#define OFF_G5   10784
#define OFF_BE5  11040
#define W_TOTAL  11296
// stats arena (floats): sums1[1024] | sums2[2048] | sums345[1536]
#define NSUMS    4608

struct WPtrs { const void* p[15]; };

typedef __attribute__((ext_vector_type(8))) short short8;
typedef __attribute__((ext_vector_type(4))) float f32x4;

__device__ inline float bf2f(__hip_bfloat16 v) { return __bfloat162float(v); }
__device__ inline float bfu(unsigned short u) { return __uint_as_float((unsigned)u << 16); }

// ---------------------------------------------------------------------------
// k_prep: per-block self-sniff (fp32 vs bf16), convert weights to bf16 arena,
// zero the raw-sums region; block 0 publishes the flag for later kernels.
// ---------------------------------------------------------------------------
__global__ __launch_bounds__(256) void k_prep(const unsigned short* __restrict__ xr,
                                              WPtrs wp,
                                              __hip_bfloat16* __restrict__ wc,
                                              float* __restrict__ sums,
                                              int* __restrict__ flag) {
    int tid = threadIdx.x;
    int cnt = 0;
    for (int i = tid; i < 2048; i += 256) {
        int e = (xr[i] >> 7) & 0xFF;
        if (e >= 134) cnt++;
    }
    for (int o = 1; o < 64; o <<= 1) cnt += __shfl_xor(cnt, o, 64);
    __shared__ int sh[4];
    if ((tid & 63) == 0) sh[tid >> 6] = cnt;
    __syncthreads();
    int f = (sh[0] + sh[1] + sh[2] + sh[3] >= 32) ? 1 : 0;
    if (blockIdx.x == 0 && tid == 0) *flag = f;

    const int sizes[15] = {4096, 256, 16, 2304, 16, 512, 512, 1024, 1024,
                           256, 256, 256, 256, 256, 256};
    int i = blockIdx.x * 256 + tid;
    if (i < W_TOTAL) {
        int seg = 0, off = 0;
        while (i >= off + sizes[seg]) { off += sizes[seg]; seg++; }
        int j = i - off;
        float v = f ? ((const float*)wp.p[seg])[j]
                    : bf2f(((const __hip_bfloat16*)wp.p[seg])[j]);
        wc[i] = __float2bfloat16(v);
    }
    if (i < NSUMS) sums[i] = 0.f;
}

// ---------------------------------------------------------------------------
// Fused LIF + Haar-W. Planar coalesced u8 spikes + i8 Haar codes + BN1 sums.
// Block = (b, c, half); thread = (row-in-half, w-pair).
// ---------------------------------------------------------------------------
__global__ __launch_bounds__(256) void k_lifhaar(const void* __restrict__ x_,
                                                 const int* __restrict__ flag,
                                                 unsigned char* __restrict__ s,
                                                 signed char* __restrict__ l1,
                                                 float* __restrict__ sums1) {
    int bid = blockIdx.x;                      // 2048 = b(4) * c(256) * half(2)
    int tid = threadIdx.x;
    int half = bid & 1;
    int c = (bid >> 1) & 255;
    int b = bid >> 9;
    int wp = tid & 15;
    int hl = tid >> 4;
    int h = half * 16 + hl;
    int f = *flag;
    const float* xf = (const float*)x_;
    const unsigned int* xb = (const unsigned int*)x_;
    int n = ((b * 256 + c) * 32 + h) * 32 + 2 * wp;

    float v0 = 0.f, v1 = 0.f;
    float aL = 0.f, qL = 0.f, aH = 0.f, qH = 0.f;
    #pragma unroll
    for (int t = 0; t < T_; ++t) {
        size_t idx = (size_t)t * 1048576 + n;
        float x0, x1;
        if (f) {
            float2 xx = *(const float2*)(xf + idx);
            x0 = xx.x; x1 = xx.y;
        } else {
            unsigned int u = xb[idx >> 1];
            x0 = __uint_as_float(u << 16);
            x1 = __uint_as_float(u & 0xffff0000u);
        }
        v0 += (x0 - v0) * 0.5f;
        v1 += (x1 - v1) * 0.5f;
        float s0 = (v0 >= 1.f) ? 1.f : 0.f;
        float s1 = (v1 >= 1.f) ? 1.f : 0.f;
        v0 *= (1.f - s0);
        v1 *= (1.f - s1);
        int tb = t * 4 + b;
        ((uchar2*)s)[(size_t)(tb * 256 + c) * 512 + h * 16 + wp] =
            make_uchar2((unsigned char)s0, (unsigned char)s1);
        float cl = s0 + s1, ch = s0 - s1;
        size_t lb = (((size_t)tb * 512 + c) * 32 + h) * 16 + wp;
        l1[lb] = (signed char)(int)cl;
        l1[lb + (size_t)256 * 512] = (signed char)(int)ch;
        aL += cl; qL += cl * cl; aH += ch; qH += ch * ch;
    }
    for (int o = 1; o < 64; o <<= 1) {
        aL += __shfl_xor(aL, o, 64); qL += __shfl_xor(qL, o, 64);
        aH += __shfl_xor(aH, o, 64); qH += __shfl_xor(qH, o, 64);
    }
    __shared__ float part[4][4];
    int lane = tid & 63, wv = tid >> 6;
    if (lane == 0) {
        part[wv][0] = aL; part[wv][1] = qL; part[wv][2] = aH; part[wv][3] = qH;
    }
    __syncthreads();
    if (tid < 4) {
        float tot = part[0][tid] + part[1][tid] + part[2][tid] + part[3][tid];
        const int offs[4] = {0, 512, 256, 768};
        atomicAdd(&sums1[offs[tid] + c], tot);
    }
}

// ---------------------------------------------------------------------------
// Fused k_work: bids [0,256) = conv role (MFMA implicit GEMM w/ LDS-staged
// channel-last spikes + BN4/5 sum accumulation); bids [256,4352) = stage2
// role (BN1-apply + Haar-H + gates -> l2, BN2 sum accumulation).
// ---------------------------------------------------------------------------
struct SharedU {
    union {
        struct {
            short lo[1025 * 8];            // channel-last bf16, d 0..7 (+zero row)
            short hi[1025 * 8];            // d 8..15
            unsigned short w2s[2304];      // [k][d*9+tap]
            unsigned short w1s[256];       // [k][d]
            unsigned short bs[32];         // B1 | B2
            float parts[4][4][16];         // [wv][g][r*4+which]
        } cv;
        struct {
            float lo[512];
            float hi[512];
            float part[4][8];
        } s2;
    };
};

__global__ __launch_bounds__(256) void k_work(const unsigned char* __restrict__ s,
                                              const signed char* __restrict__ l1,
                                              const float* __restrict__ sums1,
                                              const __hip_bfloat16* __restrict__ wc,
                                              float* __restrict__ stats,
                                              __hip_bfloat16* __restrict__ l2,
                                              __hip_bfloat16* __restrict__ c1,
                                              __hip_bfloat16* __restrict__ c2) {
    __shared__ SharedU sm;
    int bid = blockIdx.x;
    int tid = threadIdx.x;
    int lane = tid & 63, wv = tid >> 6;

    if (bid < 256) {
        // ------------------------------ conv role ------------------------------
        int img = bid;
        const unsigned short* wr = (const unsigned short*)wc;
        for (int i = tid; i < 2304; i += 256) sm.cv.w2s[i] = wr[OFF_W2 + i];
        sm.cv.w1s[tid] = wr[OFF_W1 + tid];
        if (tid < 16) { sm.cv.bs[tid] = wr[OFF_B1 + tid]; sm.cv.bs[16 + tid] = wr[OFF_B2 + tid]; }
        // zero row (pixel index 1024)
        if (tid < 8) {
            ((unsigned int*)sm.cv.lo)[4096 + (tid & 3)] = 0;
            ((unsigned int*)sm.cv.hi)[4096 + (tid & 3)] = 0;
        }
        // stage planar u8 -> LDS channel-last bf16
        {
            const unsigned int* sp = (const unsigned int*)(s + (size_t)img * 16384);
            int d2 = tid >> 5;               // channel pair 2*d2, 2*d2+1
            int pg = tid & 31;
            unsigned int* dst = (unsigned int*)((d2 < 4) ? sm.cv.lo : sm.cv.hi);
            int dl = d2 & 3;
            #pragma unroll
            for (int p = 0; p < 8; ++p) {
                int base = p * 32 + pg;      // dword index within a channel row
                unsigned int u0 = sp[d2 * 512 + base];
                unsigned int u1 = sp[d2 * 512 + 256 + base];
                #pragma unroll
                for (int jj = 0; jj < 4; ++jj) {
                    int j = (jj + pg) & 3;   // scramble to spread LDS banks
                    unsigned int b0 = (u0 >> (8 * j)) & 255u;
                    unsigned int b1 = (u1 >> (8 * j)) & 255u;
                    unsigned int val = (b0 ? 0x3F80u : 0u) | ((b1 ? 0x3F80u : 0u) << 16);
                    int pix = p * 128 + pg * 4 + j;
                    dst[pix * 4 + dl] = val;
                }
            }
        }
        __syncthreads();

        int m = lane & 15;
        int g = lane >> 4;
        const int tapA[5] = {0, 2, 4, 6, 8};
        const int tapB[5] = {1, 3, 5, 7, 8};

        short8 afr[5], a1f;
        #pragma unroll
        for (int p = 0; p < 5; ++p) {
            int tap = (g < 2) ? tapA[p] : tapB[p];
            short8 av;
            #pragma unroll
            for (int j = 0; j < 8; ++j) {
                int d = (g & 1) * 8 + j;
                unsigned short w = sm.cv.w2s[m * 144 + d * 9 + tap];
                if (p == 4 && g >= 2) w = 0;
                av[j] = (short)w;
            }
            afr[p] = av;
        }
        #pragma unroll
        for (int j = 0; j < 8; ++j) {
            int d = (g & 1) * 8 + j;
            a1f[j] = (g < 2) ? (short)sm.cv.w1s[m * 16 + d] : (short)0;
        }
        float bias1[4], bias2[4];
        #pragma unroll
        for (int r = 0; r < 4; ++r) {
            bias1[r] = bfu(sm.cv.bs[g * 4 + r]);
            bias2[r] = bfu(sm.cv.bs[16 + g * 4 + r]);
        }

        __hip_bfloat16* o1 = c1 + (size_t)img * 16384;
        __hip_bfloat16* o2 = c2 + (size_t)img * 16384;
        const short* bsrc = (g & 1) ? sm.cv.hi : sm.cv.lo;

        float cs1[4] = {0, 0, 0, 0}, cq1[4] = {0, 0, 0, 0};
        float cs2[4] = {0, 0, 0, 0}, cq2[4] = {0, 0, 0, 0};

        for (int t = wv * 16; t < wv * 16 + 16; ++t) {
            int h = t >> 1;
            int w0 = (t & 1) << 4;
            f32x4 acc2 = {0.f, 0.f, 0.f, 0.f};
            f32x4 acc1 = {0.f, 0.f, 0.f, 0.f};
            #pragma unroll
            for (int p = 0; p < 5; ++p) {
                int tap = (g < 2) ? tapA[p] : tapB[p];
                int row = h + tap / 3 - 1;
                int col = w0 + m + (tap % 3) - 1;
                bool ok = ((unsigned)row < 32u) && ((unsigned)col < 32u);
                int idx = ok ? (row * 32 + col) : 1024;
                short8 bv = *(const short8*)&bsrc[idx * 8];
                acc2 = __builtin_amdgcn_mfma_f32_16x16x32_bf16(afr[p], bv, acc2, 0, 0, 0);
                if (p == 2)
                    acc1 = __builtin_amdgcn_mfma_f32_16x16x32_bf16(a1f, bv, acc1, 0, 0, 0);
            }
            int pix = h * 32 + w0 + m;
            #pragma unroll
            for (int r = 0; r < 4; ++r) {
                int k = g * 4 + r;
                float y1 = acc1[r] + bias1[r];
                float y2 = acc2[r] + bias2[r];
                o1[(size_t)k * 1024 + pix] = __float2bfloat16(y1);
                o2[(size_t)k * 1024 + pix] = __float2bfloat16(y2);
                cs1[r] += y1; cq1[r] += y1 * y1;
                cs2[r] += y2; cq2[r] += y2 * y2;
            }
        }
        // reduce across the 16 m-lanes (same g)
        #pragma unroll
        for (int o = 1; o < 16; o <<= 1) {
            #pragma unroll
            for (int r = 0; r < 4; ++r) {
                cs1[r] += __shfl_xor(cs1[r], o, 64);
                cq1[r] += __shfl_xor(cq1[r], o, 64);
                cs2[r] += __shfl_xor(cs2[r], o, 64);
                cq2[r] += __shfl_xor(cq2[r], o, 64);
            }
        }
        if (m == 0) {
            #pragma unroll
            for (int r = 0; r < 4; ++r) {
                sm.cv.parts[wv][g][r * 4 + 0] = cs1[r];
                sm.cv.parts[wv][g][r * 4 + 1] = cq1[r];
                sm.cv.parts[wv][g][r * 4 + 2] = cs2[r];
                sm.cv.parts[wv][g][r * 4 + 3] = cq2[r];
            }
        }
        __syncthreads();
        if (tid < 64) {
            int gg = tid >> 4, r = (tid >> 2) & 3, which = tid & 3;
            float tot = sm.cv.parts[0][gg][r * 4 + which] + sm.cv.parts[1][gg][r * 4 + which]
                      + sm.cv.parts[2][gg][r * 4 + which] + sm.cv.parts[3][gg][r * 4 + which];
            int ch = (img & 15) * 16 + gg * 4 + r;   // global BN channel
            // stats: sums4_sum@3584 sums4_sq@3840 sums5_sum@4096 sums5_sq@4352
            const int base[4] = {3584, 3840, 4096, 4352};
            atomicAdd(&stats[base[which] + ch], tot);
        }
    } else {
        // ------------------------------ stage2 role ------------------------------
        int blk = bid - 256;                  // TB*C = 4096
        int c = blk & 255;
        int tb = blk >> 8;

        const float nrm = 1.f / 8192.f;
        float mL = sums1[c] * INVS2 * nrm;
        float vL = fmaxf(sums1[512 + c] * 0.5f * nrm - mL * mL, 0.f);
        float sL = bf2f(wc[OFF_G1 + c]) * rsqrtf(vL + EPSBN);
        float tL = bf2f(wc[OFF_BE1 + c]) - mL * sL;
        float mH = sums1[256 + c] * INVS2 * nrm;
        float vH = fmaxf(sums1[768 + c] * 0.5f * nrm - mH * mH, 0.f);
        float sH = bf2f(wc[OFF_G1 + 256 + c]) * rsqrtf(vH + EPSBN);
        float tH = bf2f(wc[OFF_BE1 + 256 + c]) - mH * sH;

        const signed char* plo = l1 + (((size_t)tb * 512) + c) * (H_ * Wh_);
        const signed char* phi = l1 + (((size_t)tb * 512) + 256 + c) * (H_ * Wh_);
        float slo = sL * INVS2, shi = sH * INVS2;
        sm.s2.lo[tid & 511] = 0.f;            // placate compiler aliasing; overwritten below
        {
            sm.s2.lo[tid]       = (float)plo[tid] * slo + tL;
            sm.s2.hi[tid]       = (float)phi[tid] * shi + tH;
            sm.s2.lo[tid + 256] = (float)plo[tid + 256] * slo + tL;
            sm.s2.hi[tid + 256] = (float)phi[tid + 256] * shi + tH;
        }
        __syncthreads();

        int w = tid & 15, v = tid >> 4;
        float a = sm.s2.lo[(2 * v) * Wh_ + w], b = sm.s2.lo[(2 * v + 1) * Wh_ + w];
        float zLL = (a + b) * INVS2;
        float zHL = (a - b) * INVS2;
        a = sm.s2.hi[(2 * v) * Wh_ + w]; b = sm.s2.hi[(2 * v + 1) * Wh_ + w];
        float zLH = (a + b) * INVS2;
        float zHH = (a - b) * INVS2;
        zLL = (fabsf(zLL) - 0.5f >= 0.f) ? zLL : 0.f;
        zHL = (fabsf(zHL) - 0.5f >= 0.f) ? zHL : 0.f;
        zLH = (fabsf(zLH) - 0.5f >= 0.f) ? zLH : 0.f;
        zHH = (fabsf(zHH) - 0.5f >= 0.f) ? zHH : 0.f;

        float r0 = zLL, r1 = zHL, r2 = zLH, r3 = zHH;
        float q0 = zLL * zLL, q1 = zHL * zHL, q2 = zLH * zLH, q3 = zHH * zHH;
        for (int o = 1; o < 64; o <<= 1) {
            r0 += __shfl_xor(r0, o, 64); r1 += __shfl_xor(r1, o, 64);
            r2 += __shfl_xor(r2, o, 64); r3 += __shfl_xor(r3, o, 64);
            q0 += __shfl_xor(q0, o, 64); q1 += __shfl_xor(q1, o, 64);
            q2 += __shfl_xor(q2, o, 64); q3 += __shfl_xor(q3, o, 64);
        }
        if (lane == 0) {
            sm.s2.part[wv][0] = r0; sm.s2.part[wv][1] = r1;
            sm.s2.part[wv][2] = r2; sm.s2.part[wv][3] = r3;
            sm.s2.part[wv][4] = q0; sm.s2.part[wv][5] = q1;
            sm.s2.part[wv][6] = q2; sm.s2.part[wv][7] = q3;
        }
        __syncthreads();
        float S0 = sm.s2.part[0][0] + sm.s2.part[1][0] + sm.s2.part[2][0] + sm.s2.part[3][0];
        float S1 = sm.s2.part[0][1] + sm.s2.part[1][1] + sm.s2.part[2][1] + sm.s2.part[3][1];
        float S2 = sm.s2.part[0][2] + sm.s2.part[1][2] + sm.s2.part[2][2] + sm.s2.part[3][2];
        float S3 = sm.s2.part[0][3] + sm.s2.part[1][3] + sm.s2.part[2][3] + sm.s2.part[3][3];
        float Q0 = sm.s2.part[0][4] + sm.s2.part[1][4] + sm.s2.part[2][4] + sm.s2.part[3][4];
        float Q1 = sm.s2.part[0][5] + sm.s2.part[1][5] + sm.s2.part[2][5] + sm.s2.part[3][5];
        float Q2 = sm.s2.part[0][6] + sm.s2.part[1][6] + sm.s2.part[2][6] + sm.s2.part[3][6];
        float Q3 = sm.s2.part[0][7] + sm.s2.part[1][7] + sm.s2.part[2][7] + sm.s2.part[3][7];
        float fLL = (Q0 * (1.f / 256.f) > 0.01f) ? 1.f : 0.f;
        float fHL = (Q1 * (1.f / 256.f) > 0.02f) ? 1.f : 0.f;
        float fLH = (Q2 * (1.f / 256.f) > 0.02f) ? 1.f : 0.f;
        float fHH = (Q3 * (1.f / 256.f) > 0.05f) ? 1.f : 0.f;

        float* sums2 = stats + 1024;
        if (tid < 8) {
            const int cho[8] = {0, 1024, 256, 1280, 512, 1536, 768, 1792};
            const float vals[8] = {fLL * S0, fLL * Q0, fHL * S1, fHL * Q1,
                                   fLH * S2, fLH * Q2, fHH * S3, fHH * Q3};
            atomicAdd(&sums2[cho[tid] + c], vals[tid]);
        }

        size_t ob = (((size_t)tb * 1024) + c) * 256 + tid;
        l2[ob]               = __float2bfloat16(zLL * fLL);
        l2[ob + 256u * 256u] = __float2bfloat16(zHL * fHL);
        l2[ob + 512u * 256u] = __float2bfloat16(zLH * fLH);
        l2[ob + 768u * 256u] = __float2bfloat16(zHH * fHH);
    }
}

// ---------------------------------------------------------------------------
// Fused BN2-apply + block channel matmul + inverse Haar -> rec bf16;
// accumulates BN3 raw sums.
// ---------------------------------------------------------------------------
__global__ __launch_bounds__(256) void k_mixinv(const __hip_bfloat16* __restrict__ l2,
                                                const __hip_bfloat16* __restrict__ wc,
                                                float* __restrict__ stats,
                                                __hip_bfloat16* __restrict__ rec) {
    int bid = blockIdx.x;                 // 256 = tb(16) * cg(16)
    int cg = bid & 15;
    int tb = bid >> 4;
    int tid = threadIdx.x;
    int lane = tid & 63, wvv = tid >> 6;
    const float* sums2 = stats + 1024;

    __shared__ float wt[4][16][16];       // [q][d][k]
    __shared__ float bsc[64], bsh[64];
    __shared__ float parts2[4][32];
    for (int i = tid; i < 1024; i += 256) {
        int q = i >> 8, rem = i & 255, d = rem >> 4, k = rem & 15;
        int nb = q * 4 + (cg >> 2);
        wt[q][d][k] = bf2f(wc[OFF_HW + nb * 256 + d * 16 + k]);
    }
    if (tid < 64) {
        int q = tid >> 4, d = tid & 15;
        int ch = q * 256 + cg * 16 + d;
        float m = sums2[ch] * (1.f / 4096.f);
        float var = fmaxf(sums2[1024 + ch] * (1.f / 4096.f) - m * m, 0.f);
        float sc = bf2f(wc[OFF_G2 + ch]) * rsqrtf(var + EPSBN);
        bsc[tid] = sc;
        bsh[tid] = bf2f(wc[OFF_BE2 + ch]) - m * sc;
    }
    __syncthreads();

    float h[4][16];
    #pragma unroll
    for (int q = 0; q < 4; ++q)
        #pragma unroll
        for (int k = 0; k < 16; ++k) h[q][k] = 0.f;

    int p = tid;
    #pragma unroll
    for (int q = 0; q < 4; ++q) {
        const __hip_bfloat16* base =
            l2 + ((size_t)tb * 1024 + q * 256 + cg * 16) * 256 + p;
        #pragma unroll
        for (int d = 0; d < 16; ++d) {
            float xv = bf2f(base[d * 256]) * bsc[q * 16 + d] + bsh[q * 16 + d];
            #pragma unroll
            for (int k = 0; k < 16; ++k)
                h[q][k] = fmaf(xv, wt[q][d][k], h[q][k]);
        }
    }

    int uh = tid >> 4, uw = tid & 15;
    __hip_bfloat16* ob = rec + ((size_t)tb * 256 + cg * 16) * 1024;
    float sk[16], qk[16];
    #pragma unroll
    for (int k = 0; k < 16; ++k) {
        float LL = h[0][k], HL = h[1][k], LH = h[2][k], HH = h[3][k];
        float v00 = 0.5f * (LL + HL + LH + HH);
        float v01 = 0.5f * (LL + HL - LH - HH);
        float v10 = 0.5f * (LL - HL + LH - HH);
        float v11 = 0.5f * (LL - HL - LH + HH);
        __hip_bfloat162 top, bot;
        top.x = __float2bfloat16(v00); top.y = __float2bfloat16(v01);
        bot.x = __float2bfloat16(v10); bot.y = __float2bfloat16(v11);
        *(__hip_bfloat162*)(ob + (size_t)k * 1024 + (2 * uh) * 32 + 2 * uw) = top;
        *(__hip_bfloat162*)(ob + (size_t)k * 1024 + (2 * uh + 1) * 32 + 2 * uw) = bot;
        sk[k] = v00 + v01 + v10 + v11;
        qk[k] = v00 * v00 + v01 * v01 + v10 * v10 + v11 * v11;
    }
    for (int o = 1; o < 64; o <<= 1) {
        #pragma unroll
        for (int k = 0; k < 16; ++k) {
            sk[k] += __shfl_xor(sk[k], o, 64);
            qk[k] += __shfl_xor(qk[k], o, 64);
        }
    }
    if (lane == 0) {
        #pragma unroll
        for (int k = 0; k < 16; ++k) {
            parts2[wvv][k * 2]     = sk[k];
            parts2[wvv][k * 2 + 1] = qk[k];
        }
    }
    __syncthreads();
    if (tid < 32) {
        int k = tid >> 1, which = tid & 1;
        float tot = parts2[0][tid] + parts2[1][tid] + parts2[2][tid] + parts2[3][tid];
        atomicAdd(&stats[3072 + which * 256 + cg * 16 + k], tot);
    }
}

// ---------------------------------------------------------------------------
// Final combine; derives BN3/4/5 coefficients from raw sums (block = one
// half-channel, so coefficients are block-uniform).
// ---------------------------------------------------------------------------
__global__ __launch_bounds__(256) void k_final(const __hip_bfloat16* __restrict__ rec,
                                               const __hip_bfloat16* __restrict__ c1,
                                               const __hip_bfloat16* __restrict__ c2,
                                               const float* __restrict__ stats,
                                               const __hip_bfloat16* __restrict__ wc,
                                               const int* __restrict__ flag,
                                               void* __restrict__ out_) {
    int n2 = blockIdx.x * 256 + threadIdx.x;    // bf162 index
    int c = ((n2 * 2) >> 10) & 255;
    const float inv = 1.f / 16384.f;
    float m3 = stats[3072 + c] * inv;
    float v3 = fmaxf(stats[3328 + c] * inv - m3 * m3, 0.f);
    float sc3 = bf2f(wc[OFF_G3 + c]) * rsqrtf(v3 + EPSBN);
    float sh3 = bf2f(wc[OFF_BE3 + c]) - m3 * sc3;
    float m4 = stats[3584 + c] * inv;
    float v4 = fmaxf(stats[3840 + c] * inv - m4 * m4, 0.f);
    float sc4 = bf2f(wc[OFF_G4 + c]) * rsqrtf(v4 + EPSBN);
    float sh4 = bf2f(wc[OFF_BE4 + c]) - m4 * sc4;
    float m5 = stats[4096 + c] * inv;
    float v5 = fmaxf(stats[4352 + c] * inv - m5 * m5, 0.f);
    float sc5 = bf2f(wc[OFF_G5 + c]) * rsqrtf(v5 + EPSBN);
    float sh5 = bf2f(wc[OFF_BE5 + c]) - m5 * sc5;

    __hip_bfloat162 r = ((const __hip_bfloat162*)rec)[n2];
    __hip_bfloat162 a = ((const __hip_bfloat162*)c1)[n2];
    __hip_bfloat162 b = ((const __hip_bfloat162*)c2)[n2];
    float v0 = bf2f(r.x) * sc3 + sh3 + bf2f(a.x) * sc4 + sh4 + bf2f(b.x) * sc5 + sh5;
    float v1 = bf2f(r.y) * sc3 + sh3 + bf2f(a.y) * sc4 + sh4 + bf2f(b.y) * sc5 + sh5;
    if (*flag) {
        ((float2*)out_)[n2] = make_float2(v0, v1);
    } else {
        __hip_bfloat162 o;
        o.x = __float2bfloat16(v0); o.y = __float2bfloat16(v1);
        ((__hip_bfloat162*)out_)[n2] = o;
    }
}

// ---------------------------------------------------------------------------
// Workspace map (ws_size >= 256 MiB per R4 fill profile; we use 40.2 MB):
//   [0,4M):   s (planar u8 spikes)      [4,8M):  l1 (i8 codes)
//   [8,16M):  l2                        [16,24M): rec
//   [24,32M): c1                        [32,40M): c2
//   [40M..):  weight arena, stats(4608 fl), flag
// ---------------------------------------------------------------------------
extern "C" void kernel_launch(void* const* d_in, const int* in_sizes, int n_in,
                              void* d_out, int out_size, void* d_ws, size_t ws_size,
                              hipStream_t stream) {
    char* ws = (char*)d_ws;
    unsigned char* s_u8  = (unsigned char*)ws;
    signed char* l1c     = (signed char*)(ws + ((size_t)4 << 20));
    __hip_bfloat16* l2   = (__hip_bfloat16*)(ws + ((size_t)8 << 20));
    __hip_bfloat16* rec  = (__hip_bfloat16*)(ws + ((size_t)16 << 20));
    __hip_bfloat16* c1   = (__hip_bfloat16*)(ws + ((size_t)24 << 20));
    __hip_bfloat16* c2   = (__hip_bfloat16*)(ws + ((size_t)32 << 20));
    __hip_bfloat16* wc   = (__hip_bfloat16*)(ws + ((size_t)40 << 20));
    float* stats         = (float*)(ws + ((size_t)40 << 20) + (64 << 10));
    int* flag            = (int*)(ws + ((size_t)40 << 20) + (128 << 10));

    WPtrs wp;
    for (int i = 0; i < 15; ++i) wp.p[i] = d_in[i + 1];

    dim3 blk(256);
    k_prep<<<dim3(45), blk, 0, stream>>>((const unsigned short*)d_in[0], wp, wc, stats, flag);
    k_lifhaar<<<dim3(2048), blk, 0, stream>>>(d_in[0], flag, s_u8, l1c, stats);
    k_work<<<dim3(4352), blk, 0, stream>>>(s_u8, l1c, stats, wc, stats, l2, c1, c2);
    k_mixinv<<<dim3(256), blk, 0, stream>>>(l2, wc, stats, rec);
    k_final<<<dim3(8192), blk, 0, stream>>>(rec, c1, c2, stats, wc, flag, d_out);
}